// Round 13
// baseline (139.757 us; speedup 1.0000x reference)
//
#include <hip/hip_runtime.h>
#include <hip/hip_bf16.h>

// UnifiedAttention: x->QKV gemm -> causal MHA (H=16,D=64) -> proj gemm
// B=2, N=2048, C=1024. bf16 MFMA with fp32 accum throughout.

typedef __bf16 bf16x8 __attribute__((ext_vector_type(8)));
typedef __bf16 bf16x4 __attribute__((ext_vector_type(4)));
typedef __bf16 bf16x2 __attribute__((ext_vector_type(2)));
typedef float  f32x4  __attribute__((ext_vector_type(4)));
typedef float  f32x16 __attribute__((ext_vector_type(16)));
typedef int    i32x4  __attribute__((ext_vector_type(4)));

#define MFMA16(a, b, c) __builtin_amdgcn_mfma_f32_16x16x32_bf16((a), (b), (c), 0, 0, 0)
#define MFMA32(a, b, c) __builtin_amdgcn_mfma_f32_32x32x16_bf16((a), (b), (c), 0, 0, 0)

__device__ __forceinline__ void async_copy16(const __bf16* g, __bf16* l) {
    __builtin_amdgcn_global_load_lds(
        (const __attribute__((address_space(1))) void*)g,
        (__attribute__((address_space(3))) void*)l,
        16, 0, 0);
}

__device__ __forceinline__ unsigned packbf(float a, float b) {
    union { bf16x2 v; unsigned u; } un;
    un.v[0] = (__bf16)a; un.v[1] = (__bf16)b;
    return un.u;
}

// -------- fp32 -> bf16 conversion, all three tensors in one launch ------------
// counts in float4 QUADS: x 1048576, qkv_w 786432, proj_w 262144 -> 8192 x 256.
__global__ void f32_to_bf16_3k(const float* __restrict__ a, __bf16* __restrict__ ad, int na,
                               const float* __restrict__ b, __bf16* __restrict__ bd, int nb,
                               const float* __restrict__ c, __bf16* __restrict__ cd, int nc)
{
    int i = blockIdx.x * blockDim.x + threadIdx.x;  // quad index
    const float* src; __bf16* dst; int j;
    if (i < na)            { src = a; dst = ad; j = i; }
    else if (i < na + nb)  { src = b; dst = bd; j = i - na; }
    else if (i < na + nb + nc) { src = c; dst = cd; j = i - na - nb; }
    else return;
    float4 v = reinterpret_cast<const float4*>(src)[j];
    bf16x4 o;
    o[0] = (__bf16)v.x; o[1] = (__bf16)v.y; o[2] = (__bf16)v.z; o[3] = (__bf16)v.w;
    reinterpret_cast<bf16x4*>(dst)[j] = o;
}

// ---------------- mask tile reduction: 64x64 tiles -> all-ones flag ----------------
__global__ void mask_reduce_k(const int* __restrict__ mask, int* __restrict__ mflag) {
    __shared__ int ok;
    const int t = threadIdx.x;
    if (t == 0) ok = 1;
    __syncthreads();
    const int jt = blockIdx.x & 31;
    const int it = (blockIdx.x >> 5) & 31;
    const int b  = blockIdx.x >> 10;
    bool all1 = true;
#pragma unroll
    for (int c = 0; c < 4; ++c) {
        const int row = c * 16 + (t >> 4);
        const int col = (t & 15) * 4;
        const int4 v = *reinterpret_cast<const int4*>(
            &mask[((size_t)(b * 2048 + it * 64 + row)) * 2048 + jt * 64 + col]);
        all1 = all1 && v.x && v.y && v.z && v.w;
    }
    if (!all1) ok = 0;
    __syncthreads();
    if (t == 0) mflag[(b * 32 + it) * 32 + jt] = ok;
}

// ============ 8-phase 256x256 QKV GEMM (T1+T2+T3+T4+T5), K=1024 =================
#define BAR() asm volatile("s_barrier" ::: "memory")
#define VM2() asm volatile("s_waitcnt vmcnt(2)" ::: "memory")
#define VM4() asm volatile("s_waitcnt vmcnt(4)" ::: "memory")
#define VM6() asm volatile("s_waitcnt vmcnt(6)" ::: "memory")

__global__ __launch_bounds__(512, 2) void gemm_qkv8_k(
    const __bf16* __restrict__ A, const __bf16* __restrict__ Bm,
    const float* __restrict__ bias,
    __bf16* __restrict__ qg, __bf16* __restrict__ kg, __bf16* __restrict__ vtg)
{
    __shared__ __align__(16) __bf16 As[2][16384];   // [buf][256 rows x 64]
    __shared__ __align__(16) __bf16 Bs[2][16384];

    const int t = threadIdx.x;
    const int lane = t & 63;
    const int w = t >> 6;
    const int wr = w >> 2, wc = w & 3;
    const int li = lane & 15, g = lane >> 4;

    // XCD-aware bijective swizzle (grid=192, 192%8==0, 24 blocks per XCD)
    const int bid = (blockIdx.x & 7) * 24 + (blockIdx.x >> 3);
    const int m0 = (bid / 12) << 8;     // N tiles = 3072/256 = 12
    const int n0 = (bid % 12) << 8;

    const int srow = t >> 3;
    const int scol = ((t & 7) ^ (srow & 7)) << 3;
    const __bf16* pA = A  + (size_t)(m0 + srow) * 1024 + scol;
    const __bf16* pB = Bm + (size_t)(n0 + srow) * 1024 + scol;
    __bf16* dA = &As[0][0] + t * 8;
    __bf16* dB = &Bs[0][0] + t * 8;

#define STAGE_A(BB, T, HH) do {                                                   \
    const size_t ro_ = (size_t)((HH) * 128) * 1024 + (size_t)(T) * 64;            \
    async_copy16(pA + ro_,         dA + (BB) * 16384 + (HH) * 8192);              \
    async_copy16(pA + ro_ + 65536, dA + (BB) * 16384 + (HH) * 8192 + 4096);       \
  } while (0)
#define STAGE_B(BB, T, HH) do {                                                   \
    const size_t ro_ = (size_t)((HH) * 128) * 1024 + (size_t)(T) * 64;            \
    async_copy16(pB + ro_,         dB + (BB) * 16384 + (HH) * 8192);              \
    async_copy16(pB + ro_ + 65536, dB + (BB) * 16384 + (HH) * 8192 + 4096);       \
  } while (0)

    const int aoff0 = ((0 + g) ^ (li & 7)) << 3;
    const int aoff1 = ((4 + g) ^ (li & 7)) << 3;
    const int abase = (wr * 128 + li) * 64;
    const int bbase = (wc * 64 + li) * 64;

    f32x4 acc[8][4] = {};
    bf16x8 a[4][2], b[2][2][2];

#define READ_A(BB, MH) do { _Pragma("unroll")                                     \
    for (int mi2 = 0; mi2 < 4; ++mi2) {                                           \
      const __bf16* p_ = &As[BB][abase + ((MH) * 4 + mi2) * 1024];                \
      a[mi2][0] = *reinterpret_cast<const bf16x8*>(p_ + aoff0);                   \
      a[mi2][1] = *reinterpret_cast<const bf16x8*>(p_ + aoff1); } } while (0)
#define READ_B(BB, NH) do { _Pragma("unroll")                                     \
    for (int ni2 = 0; ni2 < 2; ++ni2) {                                           \
      const __bf16* p_ = &Bs[BB][bbase + ((NH) * 2 + ni2) * 1024];                \
      b[NH][ni2][0] = *reinterpret_cast<const bf16x8*>(p_ + aoff0);               \
      b[NH][ni2][1] = *reinterpret_cast<const bf16x8*>(p_ + aoff1); } } while (0)
#define MFMA_QUAD(MH, NH) do {                                                    \
    __builtin_amdgcn_s_setprio(1);                                                \
    _Pragma("unroll") for (int mi2 = 0; mi2 < 4; ++mi2)                           \
    _Pragma("unroll") for (int ni2 = 0; ni2 < 2; ++ni2) {                         \
      f32x4 c_ = acc[(MH) * 4 + mi2][(NH) * 2 + ni2];                             \
      c_ = MFMA16(a[mi2][0], b[NH][ni2][0], c_);                                  \
      c_ = MFMA16(a[mi2][1], b[NH][ni2][1], c_);                                  \
      acc[(MH) * 4 + mi2][(NH) * 2 + ni2] = c_; }                                 \
    __builtin_amdgcn_s_setprio(0); } while (0)

#define KTILE(BB, T) do {                                                         \
    const int Tn_  = ((T) + 1 < 16) ? (T) + 1 : 15;                               \
    const int Tn2_ = ((T) + 2 < 16) ? (T) + 2 : 15;                               \
    STAGE_A((BB) ^ 1, Tn_, 1);                                                    \
    READ_A(BB, 0); READ_B(BB, 0);                                                 \
    BAR(); MFMA_QUAD(0, 0); BAR();                                                \
    STAGE_B((BB) ^ 1, Tn_, 0);                                                    \
    READ_B(BB, 1);                                                                \
    BAR(); MFMA_QUAD(0, 1); BAR();                                                \
    STAGE_B((BB) ^ 1, Tn_, 1);                                                    \
    READ_A(BB, 1);                                                                \
    BAR(); MFMA_QUAD(1, 0); BAR();                                                \
    STAGE_A((BB), Tn2_, 0);                                                       \
    VM2(); BAR(); MFMA_QUAD(1, 1); BAR();                                         \
  } while (0)

    STAGE_A(0, 0, 0); STAGE_A(0, 0, 1);
    STAGE_B(0, 0, 0); STAGE_B(0, 0, 1);
    STAGE_A(1, 1, 0);
    VM2(); BAR();

#pragma unroll 1
    for (int jj = 0; jj < 8; ++jj) {
        KTILE(0, 2 * jj);
        KTILE(1, 2 * jj + 1);
    }

    // ---- epilogue: scatter into q (scaled by 0.125*log2e for exp2 softmax) / k / vT
    const int nbase = n0 + wc * 64;
    const int s = nbase >> 10;
    const int headg = (m0 >> 11) * 16 + ((nbase & 1023) >> 6);
    const int mrow = (m0 & 2047) + wr * 128 + g * 4;
    float bv[4];
#pragma unroll
    for (int ni = 0; ni < 4; ++ni) bv[ni] = bias[nbase + ni * 16 + li];

    if (s == 2) {
#pragma unroll
        for (int mi = 0; mi < 8; ++mi) {
#pragma unroll
            for (int ni = 0; ni < 4; ++ni) {
                bf16x4 st;
#pragma unroll
                for (int r = 0; r < 4; ++r) st[r] = (__bf16)(acc[mi][ni][r] + bv[ni]);
                *reinterpret_cast<bf16x4*>(
                    &vtg[((size_t)(headg * 64) + ni * 16 + li) * 2048 + mrow + mi * 16]) = st;
            }
        }
    } else {
        __bf16* og = (s == 0) ? qg : kg;
        const float sc = (s == 0) ? 0.18033688f : 1.0f;   // 0.125 * log2(e)
#pragma unroll
        for (int mi = 0; mi < 8; ++mi) {
#pragma unroll
            for (int r = 0; r < 4; ++r) {
                __bf16* rp = og + ((size_t)headg * 2048 + mrow + mi * 16 + r) * 64;
#pragma unroll
                for (int ni = 0; ni < 4; ++ni)
                    rp[ni * 16 + li] = (__bf16)((acc[mi][ni][r] + bv[ni]) * sc);
            }
        }
    }
#undef KTILE
#undef MFMA_QUAD
#undef READ_A
#undef READ_B
#undef STAGE_A
#undef STAGE_B
}

// ------- proj GEMM: 128x64 tile, BK=64, 3-buffer counted-vmcnt (distance-1) -------
__global__ __launch_bounds__(256) void gemm_proj_k(
    const __bf16* __restrict__ A, const __bf16* __restrict__ Bm,
    const float* __restrict__ bias, float* __restrict__ outf)
{
    __shared__ __align__(16) __bf16 As[3][8192];   // [buf][128 r x 64], XOR-swz slots
    __shared__ __align__(16) __bf16 Bs[3][4096];   // [buf][64 r x 64], XOR-swz
    const int t = threadIdx.x;
    const int lane = t & 63, w = t >> 6;
    const int li = lane & 15, g = lane >> 4;
    const int wr = w >> 1, wc = w & 1;
    const int sw7 = li & 7;
    const int bid = (blockIdx.x & 7) * 64 + (blockIdx.x >> 3);
    const int m0 = (bid >> 4) << 7;   // 32 m-tiles
    const int n0 = (bid & 15) << 6;   // 16 n-tiles

#define PSTAGE(BUF, KT) do {                                                      \
    _Pragma("unroll")                                                             \
    for (int c_ = 0; c_ < 4; ++c_) {                                              \
        const int row_ = c_ * 32 + (t >> 3);                                      \
        async_copy16(A + (size_t)(m0 + row_) * 1024 + ((KT) << 6)                 \
                       + (((t & 7) ^ (row_ & 7)) << 3),                           \
                     &As[BUF][0] + c_ * 2048 + t * 8);                            \
    }                                                                             \
    _Pragma("unroll")                                                             \
    for (int c_ = 0; c_ < 2; ++c_) {                                              \
        const int row_ = c_ * 32 + (t >> 3);                                      \
        async_copy16(Bm + (size_t)(n0 + row_) * 1024 + ((KT) << 6)                \
                       + (((t & 7) ^ (row_ & 7)) << 3),                           \
                     &Bs[BUF][0] + c_ * 2048 + t * 8);                            \
    }                                                                             \
} while (0)

    f32x4 acc[4][2] = {};

    PSTAGE(0, 0);
    int cur = 0;
    for (int kt = 0; kt < 16; ++kt) {
        int nxt = cur + 1; if (nxt == 3) nxt = 0;
        if (kt < 15) {
            PSTAGE(nxt, kt + 1);
            VM6();
        } else {
            asm volatile("s_waitcnt vmcnt(0)" ::: "memory");
        }
        __builtin_amdgcn_sched_barrier(0);
        __builtin_amdgcn_s_barrier();
        __builtin_amdgcn_sched_barrier(0);

        bf16x8 af[4][2], bf[2][2];
#pragma unroll
        for (int mi = 0; mi < 4; ++mi) {
            const int ra = wr * 64 + mi * 16 + li;
#pragma unroll
            for (int kk = 0; kk < 2; ++kk)
                af[mi][kk] = *reinterpret_cast<const bf16x8*>(
                    (char*)&As[cur][0] + ra * 128 + (((kk * 4 + g) ^ sw7) << 4));
        }
#pragma unroll
        for (int ni = 0; ni < 2; ++ni) {
            const int rb = wc * 32 + ni * 16 + li;
#pragma unroll
            for (int kk = 0; kk < 2; ++kk)
                bf[ni][kk] = *reinterpret_cast<const bf16x8*>(
                    (char*)&Bs[cur][0] + rb * 128 + (((kk * 4 + g) ^ sw7) << 4));
        }
        __builtin_amdgcn_s_setprio(1);
#pragma unroll
        for (int mi = 0; mi < 4; ++mi)
#pragma unroll
            for (int ni = 0; ni < 2; ++ni) {
                f32x4 c_ = acc[mi][ni];
                c_ = MFMA16(af[mi][0], bf[ni][0], c_);
                c_ = MFMA16(af[mi][1], bf[ni][1], c_);
                acc[mi][ni] = c_;
            }
        __builtin_amdgcn_s_setprio(0);
        cur = nxt;
    }
#undef PSTAGE

#pragma unroll
    for (int mi = 0; mi < 4; ++mi) {
#pragma unroll
        for (int ni = 0; ni < 2; ++ni) {
            const int n = n0 + wc * 32 + ni * 16 + li;
            const float bv = bias[n];
#pragma unroll
            for (int r = 0; r < 4; ++r) {
                const int m = m0 + wr * 64 + mi * 16 + g * 4 + r;
                outf[(size_t)m * 1024 + n] = acc[mi][ni][r] + bv;
            }
        }
    }
}

// ------- flash attention: 4 waves x 32q (MFMA32), quad-buffer counted-vmcnt -------
// Per-wave math = round-2 kernel (verified pass); schedule = round-11/12
// (verified pass). q:[BH,2048,64] (scale*log2e prefolded), k:[BH,2048,64],
// vT:[BH,64,2048]. 512 blocks x 256 thr; 4 waves x 32 queries share staged
// 64-key K/V tiles. STAGE = 4 loads -> vmcnt(4); 4 buffers (WAR-safe).
// Swapped QK^T (mfma32(K,Q)): lane pair (l31, l31+32) splits the 64 keys for
// query iq=q0w+l31 -> softmax lane-local + 1 shfl_xor(32). P redistribution
// via pack + cross-half shfl (r2 verbatim). exp2-domain + defer-max (THR=8),
// lrun reduction deferred to epilogue. LDS = 4*16KB = 64KB -> 2 blocks/CU.
__global__ __launch_bounds__(256) void attn_k(
    const __bf16* __restrict__ qg, const __bf16* __restrict__ kg,
    const __bf16* __restrict__ vtg, const int* __restrict__ mflag,
    const int* __restrict__ mask, __bf16* __restrict__ ao)
{
    __shared__ __align__(16) __bf16 Ks[4][4096];   // [64 keys][64 d], 16B-slot XOR-swz
    __shared__ __align__(16) __bf16 Vs[4][4096];   // [64 d][64 keys], XOR-swz
    const int t = threadIdx.x;
    const int w = t >> 6, lane = t & 63;
    const int h = lane >> 5, l31 = lane & 31;
    const int xcd = blockIdx.x & 7;
    const int idx = blockIdx.x >> 3;          // 0..63
    const int hg  = xcd * 4 + (idx & 3);      // 0..31
    const int q_  = idx >> 2;                 // 0..15
    const int band = (q_ < 8) ? (15 - q_) : (q_ - 8);  // heavy-first-ish pairing
    const int bI = hg >> 4, hI = hg & 15;
    const int q0w = band * 128 + w * 32;
    const int iq = q0w + l31;                 // this lane's query row
    const int mydiag = 2 * band + (w >> 1);   // wave's last 64-key tile (== mask row-tile)
    const int ktmax = 2 * band + 1;           // block's last staged tile (>=1)
    const size_t hoff = (size_t)hg * (2048 * 64);
    const __bf16* qh = qg + hoff;
    const __bf16* kh = kg + hoff;
    const __bf16* vh = vtg + hoff;
    const int rsw = l31 & 7;

    // Q B-operand frags (r2): qf[ds2] = Q[iq][ds2*16 + h*8 + j]
    bf16x8 qf[4];
#pragma unroll
    for (int ds2 = 0; ds2 < 4; ++ds2)
        qf[ds2] = *reinterpret_cast<const bf16x8*>(&qh[(size_t)iq * 64 + ds2 * 16 + h * 8]);

    f32x16 o0 = {}, o1 = {};
    float mrun = -1e30f, lrun = 0.0f;         // lrun = per-lane partial (own 32 keys)

    // stage one 64-key tile into buffer BUF: K 8KB + V 8KB, 256 thr -> 4 loads
#define STAGE(BUF, KT) do {                                                       \
    _Pragma("unroll")                                                             \
    for (int c_ = 0; c_ < 2; ++c_) {                                              \
        const int p_ = c_ * 4096 + t * 16;                                        \
        const int prow_ = p_ >> 7;                                                \
        const int pslot_ = ((p_ >> 4) & 7) ^ (prow_ & 7);                         \
        async_copy16(kh + (size_t)(((KT) << 6) + prow_) * 64 + (pslot_ << 3),     \
                     (__bf16*)((char*)(&Ks[0][0]) + (BUF) * 8192 + p_));          \
        async_copy16(vh + (size_t)prow_ * 2048 + ((KT) << 6) + (pslot_ << 3),     \
                     (__bf16*)((char*)(&Vs[0][0]) + (BUF) * 8192 + p_));          \
    }                                                                             \
} while (0)

    // prologue: tiles 0,1 in flight (4 loads each); vmcnt(4) -> tile 0 landed.
    STAGE(0, 0);
    STAGE(1, 1);
    VM4();
    __builtin_amdgcn_s_barrier();

    int cur = 0;
    for (int kt = 0; kt <= ktmax; ++kt) {
        // T4: stage 2 ahead into buffer (cur+2)&3 (tile kt-2's buffer -- readers
        // finished before barrier kt-1, already crossed). vmcnt(4) leaves only
        // the 4 just-issued loads outstanding -> tile kt+1 landed.
        if (kt + 2 <= ktmax) {
            STAGE((cur + 2) & 3, kt + 2);
            VM4();
        } else {
            asm volatile("s_waitcnt vmcnt(0)" ::: "memory");   // tail only
        }
        __builtin_amdgcn_sched_barrier(0);
        __builtin_amdgcn_s_barrier();
        __builtin_amdgcn_sched_barrier(0);
        if (kt <= mydiag) {
            const char* kb = (char*)&Ks[0][0] + cur * 8192;
            const char* vb = (char*)&Vs[0][0] + cur * 8192;
            // ---- S^T = K Q^T : lane holds S[key=crow(r,h)+32kb][query=l31] (r2)
            f32x16 s0 = {}, s1 = {};
            __builtin_amdgcn_s_setprio(1);
#pragma unroll
            for (int ds2 = 0; ds2 < 4; ++ds2) {
                const int sl = ds2 * 2 + h;
                bf16x8 kf0 = *reinterpret_cast<const bf16x8*>(
                    kb + l31 * 128 + (((sl ^ rsw)) << 4));
                bf16x8 kf1 = *reinterpret_cast<const bf16x8*>(
                    kb + (32 + l31) * 128 + (((sl ^ rsw)) << 4));
                s0 = MFMA32(kf0, qf[ds2], s0);
                s1 = MFMA32(kf1, qf[ds2], s1);
            }
            __builtin_amdgcn_s_setprio(0);
            // ---- causal / padding mask (diag tile only; pad never taken here) (r2)
            const bool pflag = (mflag[(bI * 32 + mydiag) * 32 + kt] == 0);
            if (pflag || kt == mydiag) {
                const int jb = kt * 64;
#pragma unroll
                for (int r = 0; r < 16; ++r) {
                    const int cr = (r & 3) + 8 * (r >> 2) + 4 * h;
                    const int j0 = jb + cr, j1 = jb + 32 + cr;
                    float v0 = s0[r], v1 = s1[r];
                    if (j0 > iq || (pflag && mask[((size_t)(bI * 2048 + iq)) * 2048 + j0] == 0)) v0 = -1e30f;
                    if (j1 > iq || (pflag && mask[((size_t)(bI * 2048 + iq)) * 2048 + j1] == 0)) v1 = -1e30f;
                    s0[r] = v0; s1[r] = v1;
                }
            }
            // ---- online softmax, exp2 domain, defer-max (THR=8), deferred lrun
            float mt = s0[0];
#pragma unroll
            for (int r = 1; r < 16; ++r) mt = fmaxf(mt, s0[r]);
#pragma unroll
            for (int r = 0; r < 16; ++r) mt = fmaxf(mt, s1[r]);
            mt = fmaxf(mt, __shfl_xor(mt, 32));
            if (!__all(mt <= mrun + 8.0f)) {
                const float mn = fmaxf(mrun, mt);
                const float alpha = exp2f(mrun - mn);
#pragma unroll
                for (int r = 0; r < 16; ++r) { o0[r] *= alpha; o1[r] *= alpha; }
                lrun *= alpha;
                mrun = mn;
            }
#pragma unroll
            for (int r = 0; r < 16; ++r) {
                const float p0 = exp2f(s0[r] - mrun); s0[r] = p0; lrun += p0;
                const float p1 = exp2f(s1[r] - mrun); s1[r] = p1; lrun += p1;
            }
            // ---- P redistribution to PV B-operand (pack + cross-half shfl) (r2)
            bf16x8 pa[4];
#pragma unroll
            for (int ks = 0; ks < 4; ++ks) {
                const int c0 = (ks & 1) * 8;
                unsigned A0, A1, B0, B1;
                if (ks < 2) {
                    A0 = packbf(s0[c0 + 0], s0[c0 + 1]); A1 = packbf(s0[c0 + 2], s0[c0 + 3]);
                    B0 = packbf(s0[c0 + 4], s0[c0 + 5]); B1 = packbf(s0[c0 + 6], s0[c0 + 7]);
                } else {
                    A0 = packbf(s1[c0 + 0], s1[c0 + 1]); A1 = packbf(s1[c0 + 2], s1[c0 + 3]);
                    B0 = packbf(s1[c0 + 4], s1[c0 + 5]); B1 = packbf(s1[c0 + 6], s1[c0 + 7]);
                }
                const unsigned Z0 = h ? A0 : B0;
                const unsigned Z1 = h ? A1 : B1;
                const unsigned X0 = (unsigned)__shfl_xor((int)Z0, 32);
                const unsigned X1 = (unsigned)__shfl_xor((int)Z1, 32);
                i32x4 wv;
                wv[0] = (int)(h ? X0 : A0);
                wv[1] = (int)(h ? X1 : A1);
                wv[2] = (int)(h ? B0 : X0);
                wv[3] = (int)(h ? B1 : X1);
                pa[ks] = __builtin_bit_cast(bf16x8, wv);
            }
            // ---- O += V^T P (r2)
            __builtin_amdgcn_s_setprio(1);
#pragma unroll
            for (int ks = 0; ks < 4; ++ks) {
                const int sl = ks * 2 + h;
                bf16x8 vf0 = *reinterpret_cast<const bf16x8*>(
                    vb + l31 * 128 + (((sl ^ rsw)) << 4));
                bf16x8 vf1 = *reinterpret_cast<const bf16x8*>(
                    vb + (32 + l31) * 128 + (((sl ^ rsw)) << 4));
                o0 = MFMA32(vf0, pa[ks], o0);
                o1 = MFMA32(vf1, pa[ks], o1);
            }
            __builtin_amdgcn_s_setprio(0);
        }
        cur = (cur + 1) & 3;
    }
#undef STAGE

    // ---- epilogue: finish lrun (lane pair), normalize, write (r2 verbatim)
    lrun += __shfl_xor(lrun, 32);
    const float inv = 1.0f / lrun;
    __bf16* aor = ao + ((size_t)(bI * 2048 + iq)) * 1024 + hI * 64 + h * 4;
#pragma unroll
    for (int rq = 0; rq < 4; ++rq) {
        bf16x4 st0, st1;
#pragma unroll
        for (int c2 = 0; c2 < 4; ++c2) {
            st0[c2] = (__bf16)(o0[rq * 4 + c2] * inv);
            st1[c2] = (__bf16)(o1[rq * 4 + c2] * inv);
        }
        *reinterpret_cast<bf16x4*>(&aor[rq * 8])      = st0;
        *reinterpret_cast<bf16x4*>(&aor[32 + rq * 8]) = st1;
    }
}

// ------------------------------- launch -----------------------------------------
extern "C" void kernel_launch(void* const* d_in, const int* in_sizes, int n_in,
                              void* d_out, int out_size, void* d_ws, size_t ws_size,
                              hipStream_t stream)
{
    const float* x      = (const float*)d_in[0];
    const int*   mask   = (const int*)d_in[1];
    const float* qkv_w  = (const float*)d_in[2];
    const float* qkv_b  = (const float*)d_in[3];
    const float* proj_w = (const float*)d_in[4];
    const float* proj_b = (const float*)d_in[5];
    float* out = (float*)d_out;

    char* ws = (char*)d_ws;
    __bf16* xb    = (__bf16*)(ws + 0);          // 4096x1024        8 MB
    __bf16* wqkv  = (__bf16*)(ws + 8388608);    // 3072x1024        6 MB
    __bf16* wproj = (__bf16*)(ws + 14680064);   // 1024x1024        2 MB
    __bf16* qg    = (__bf16*)(ws + 16777216);   // [32,2048,64]     8 MB
    __bf16* kg    = (__bf16*)(ws + 25165824);   // [32,2048,64]     8 MB
    __bf16* vtg   = (__bf16*)(ws + 33554432);   // [32,64,2048]     8 MB
    __bf16* ao    = (__bf16*)(ws + 41943040);   // 4096x1024        8 MB
    int*    mflag = (int*)(ws + 50331648);      // [2,32,32]        4 KB

    // quad counts: 1048576 + 786432 + 262144 = 2097152 -> 8192 blocks x 256
    f32_to_bf16_3k<<<8192, 256, 0, stream>>>(x, xb, 1048576,
                                             qkv_w, wqkv, 786432,
                                             proj_w, wproj, 262144);
    mask_reduce_k<<<2 * 32 * 32, 256, 0, stream>>>(mask, mflag);
    gemm_qkv8_k<<<192, 512, 0, stream>>>(xb, wqkv, qkv_b, qg, kg, vtg);
    attn_k<<<512, 256, 0, stream>>>(qg, kg, vtg, mflag, mask, ao);
    gemm_proj_k<<<512, 256, 0, stream>>>(ao, wproj, proj_b, out);
}

// Round 14
// 119.046 us; speedup vs baseline: 1.1740x; 1.1740x over previous
//
#include <hip/hip_runtime.h>
#include <hip/hip_bf16.h>

// UnifiedAttention: x->QKV gemm -> causal MHA (H=16,D=64) -> proj gemm
// B=2, N=2048, C=1024. bf16 MFMA with fp32 accum throughout.

typedef __bf16 bf16x8 __attribute__((ext_vector_type(8)));
typedef __bf16 bf16x4 __attribute__((ext_vector_type(4)));
typedef __bf16 bf16x2 __attribute__((ext_vector_type(2)));
typedef float  f32x4  __attribute__((ext_vector_type(4)));
typedef float  f32x16 __attribute__((ext_vector_type(16)));
typedef int    i32x4  __attribute__((ext_vector_type(4)));

#define MFMA16(a, b, c) __builtin_amdgcn_mfma_f32_16x16x32_bf16((a), (b), (c), 0, 0, 0)

__device__ __forceinline__ void async_copy16(const __bf16* g, __bf16* l) {
    __builtin_amdgcn_global_load_lds(
        (const __attribute__((address_space(1))) void*)g,
        (__attribute__((address_space(3))) void*)l,
        16, 0, 0);
}

__device__ __forceinline__ unsigned packbf(float a, float b) {
    union { bf16x2 v; unsigned u; } un;
    un.v[0] = (__bf16)a; un.v[1] = (__bf16)b;
    return un.u;
}

// -------- merged prep: fp32->bf16 conversions (blocks 0..8191) + mask reduce ------
// conv: 2097152 quads = 8192 blocks x 256 (x 1048576, qkv_w 786432, proj_w 262144).
// mask: blocks 8192..10239 -> 64x64 tile all-ones flags [2,32,32].
__global__ void prep_k(const float* __restrict__ x, __bf16* __restrict__ xb,
                       const float* __restrict__ qkvw, __bf16* __restrict__ wqkv,
                       const float* __restrict__ projw, __bf16* __restrict__ wproj,
                       const int* __restrict__ mask, int* __restrict__ mflag)
{
    if (blockIdx.x < 8192) {
        const int i = blockIdx.x * 256 + threadIdx.x;   // quad index
        const float* src; __bf16* dst; int j;
        if (i < 1048576)            { src = x;     dst = xb;    j = i; }
        else if (i < 1835008)       { src = qkvw;  dst = wqkv;  j = i - 1048576; }
        else                        { src = projw; dst = wproj; j = i - 1835008; }
        float4 v = reinterpret_cast<const float4*>(src)[j];
        bf16x4 o;
        o[0] = (__bf16)v.x; o[1] = (__bf16)v.y; o[2] = (__bf16)v.z; o[3] = (__bf16)v.w;
        reinterpret_cast<bf16x4*>(dst)[j] = o;
    } else {
        __shared__ int ok;
        const int t = threadIdx.x;
        if (t == 0) ok = 1;
        __syncthreads();
        const int bb = blockIdx.x - 8192;
        const int jt = bb & 31;
        const int it = (bb >> 5) & 31;
        const int b  = bb >> 10;
        bool all1 = true;
#pragma unroll
        for (int c = 0; c < 4; ++c) {
            const int row = c * 16 + (t >> 4);
            const int col = (t & 15) * 4;
            const int4 v = *reinterpret_cast<const int4*>(
                &mask[((size_t)(b * 2048 + it * 64 + row)) * 2048 + jt * 64 + col]);
            all1 = all1 && v.x && v.y && v.z && v.w;
        }
        if (!all1) ok = 0;
        __syncthreads();
        if (t == 0) mflag[(b * 32 + it) * 32 + jt] = ok;
    }
}

// ============ 8-phase 256x256 QKV GEMM (T1+T2+T3+T4+T5), K=1024 =================
#define BAR() asm volatile("s_barrier" ::: "memory")
#define VM2() asm volatile("s_waitcnt vmcnt(2)" ::: "memory")
#define VM6() asm volatile("s_waitcnt vmcnt(6)" ::: "memory")

__global__ __launch_bounds__(512, 2) void gemm_qkv8_k(
    const __bf16* __restrict__ A, const __bf16* __restrict__ Bm,
    const float* __restrict__ bias,
    __bf16* __restrict__ qg, __bf16* __restrict__ kg, __bf16* __restrict__ vtg)
{
    __shared__ __align__(16) __bf16 As[2][16384];   // [buf][256 rows x 64]
    __shared__ __align__(16) __bf16 Bs[2][16384];

    const int t = threadIdx.x;
    const int lane = t & 63;
    const int w = t >> 6;
    const int wr = w >> 2, wc = w & 3;
    const int li = lane & 15, g = lane >> 4;

    // XCD-aware bijective swizzle (grid=192, 192%8==0, 24 blocks per XCD)
    const int bid = (blockIdx.x & 7) * 24 + (blockIdx.x >> 3);
    const int m0 = (bid / 12) << 8;     // N tiles = 3072/256 = 12
    const int n0 = (bid % 12) << 8;

    const int srow = t >> 3;
    const int scol = ((t & 7) ^ (srow & 7)) << 3;
    const __bf16* pA = A  + (size_t)(m0 + srow) * 1024 + scol;
    const __bf16* pB = Bm + (size_t)(n0 + srow) * 1024 + scol;
    __bf16* dA = &As[0][0] + t * 8;
    __bf16* dB = &Bs[0][0] + t * 8;

#define STAGE_A(BB, T, HH) do {                                                   \
    const size_t ro_ = (size_t)((HH) * 128) * 1024 + (size_t)(T) * 64;            \
    async_copy16(pA + ro_,         dA + (BB) * 16384 + (HH) * 8192);              \
    async_copy16(pA + ro_ + 65536, dA + (BB) * 16384 + (HH) * 8192 + 4096);       \
  } while (0)
#define STAGE_B(BB, T, HH) do {                                                   \
    const size_t ro_ = (size_t)((HH) * 128) * 1024 + (size_t)(T) * 64;            \
    async_copy16(pB + ro_,         dB + (BB) * 16384 + (HH) * 8192);              \
    async_copy16(pB + ro_ + 65536, dB + (BB) * 16384 + (HH) * 8192 + 4096);       \
  } while (0)

    const int aoff0 = ((0 + g) ^ (li & 7)) << 3;
    const int aoff1 = ((4 + g) ^ (li & 7)) << 3;
    const int abase = (wr * 128 + li) * 64;
    const int bbase = (wc * 64 + li) * 64;

    f32x4 acc[8][4] = {};
    bf16x8 a[4][2], b[2][2][2];

#define READ_A(BB, MH) do { _Pragma("unroll")                                     \
    for (int mi2 = 0; mi2 < 4; ++mi2) {                                           \
      const __bf16* p_ = &As[BB][abase + ((MH) * 4 + mi2) * 1024];                \
      a[mi2][0] = *reinterpret_cast<const bf16x8*>(p_ + aoff0);                   \
      a[mi2][1] = *reinterpret_cast<const bf16x8*>(p_ + aoff1); } } while (0)
#define READ_B(BB, NH) do { _Pragma("unroll")                                     \
    for (int ni2 = 0; ni2 < 2; ++ni2) {                                           \
      const __bf16* p_ = &Bs[BB][bbase + ((NH) * 2 + ni2) * 1024];                \
      b[NH][ni2][0] = *reinterpret_cast<const bf16x8*>(p_ + aoff0);               \
      b[NH][ni2][1] = *reinterpret_cast<const bf16x8*>(p_ + aoff1); } } while (0)
#define MFMA_QUAD(MH, NH) do {                                                    \
    __builtin_amdgcn_s_setprio(1);                                                \
    _Pragma("unroll") for (int mi2 = 0; mi2 < 4; ++mi2)                           \
    _Pragma("unroll") for (int ni2 = 0; ni2 < 2; ++ni2) {                         \
      f32x4 c_ = acc[(MH) * 4 + mi2][(NH) * 2 + ni2];                             \
      c_ = MFMA16(a[mi2][0], b[NH][ni2][0], c_);                                  \
      c_ = MFMA16(a[mi2][1], b[NH][ni2][1], c_);                                  \
      acc[(MH) * 4 + mi2][(NH) * 2 + ni2] = c_; }                                 \
    __builtin_amdgcn_s_setprio(0); } while (0)

#define KTILE(BB, T) do {                                                         \
    const int Tn_  = ((T) + 1 < 16) ? (T) + 1 : 15;                               \
    const int Tn2_ = ((T) + 2 < 16) ? (T) + 2 : 15;                               \
    STAGE_A((BB) ^ 1, Tn_, 1);                                                    \
    READ_A(BB, 0); READ_B(BB, 0);                                                 \
    BAR(); MFMA_QUAD(0, 0); BAR();                                                \
    STAGE_B((BB) ^ 1, Tn_, 0);                                                    \
    READ_B(BB, 1);                                                                \
    BAR(); MFMA_QUAD(0, 1); BAR();                                                \
    STAGE_B((BB) ^ 1, Tn_, 1);                                                    \
    READ_A(BB, 1);                                                                \
    BAR(); MFMA_QUAD(1, 0); BAR();                                                \
    STAGE_A((BB), Tn2_, 0);                                                       \
    VM2(); BAR(); MFMA_QUAD(1, 1); BAR();                                         \
  } while (0)

    STAGE_A(0, 0, 0); STAGE_A(0, 0, 1);
    STAGE_B(0, 0, 0); STAGE_B(0, 0, 1);
    STAGE_A(1, 1, 0);
    VM2(); BAR();

#pragma unroll 1
    for (int jj = 0; jj < 8; ++jj) {
        KTILE(0, 2 * jj);
        KTILE(1, 2 * jj + 1);
    }

    // ---- epilogue: scatter into q (scaled by 0.125*log2e for exp2 softmax) / k / vT
    const int nbase = n0 + wc * 64;
    const int s = nbase >> 10;
    const int headg = (m0 >> 11) * 16 + ((nbase & 1023) >> 6);
    const int mrow = (m0 & 2047) + wr * 128 + g * 4;
    float bv[4];
#pragma unroll
    for (int ni = 0; ni < 4; ++ni) bv[ni] = bias[nbase + ni * 16 + li];

    if (s == 2) {
#pragma unroll
        for (int mi = 0; mi < 8; ++mi) {
#pragma unroll
            for (int ni = 0; ni < 4; ++ni) {
                bf16x4 st;
#pragma unroll
                for (int r = 0; r < 4; ++r) st[r] = (__bf16)(acc[mi][ni][r] + bv[ni]);
                *reinterpret_cast<bf16x4*>(
                    &vtg[((size_t)(headg * 64) + ni * 16 + li) * 2048 + mrow + mi * 16]) = st;
            }
        }
    } else {
        __bf16* og = (s == 0) ? qg : kg;
        const float sc = (s == 0) ? 0.18033688f : 1.0f;   // 0.125 * log2(e)
#pragma unroll
        for (int mi = 0; mi < 8; ++mi) {
#pragma unroll
            for (int r = 0; r < 4; ++r) {
                __bf16* rp = og + ((size_t)headg * 2048 + mrow + mi * 16 + r) * 64;
#pragma unroll
                for (int ni = 0; ni < 4; ++ni)
                    rp[ni * 16 + li] = (__bf16)((acc[mi][ni][r] + bv[ni]) * sc);
            }
        }
    }
#undef KTILE
#undef MFMA_QUAD
#undef READ_A
#undef READ_B
#undef STAGE_A
#undef STAGE_B
}

// ------- proj GEMM: 128x64 tile, BK=64, 3-buffer counted-vmcnt (distance-1) -------
__global__ __launch_bounds__(256) void gemm_proj_k(
    const __bf16* __restrict__ A, const __bf16* __restrict__ Bm,
    const float* __restrict__ bias, float* __restrict__ outf)
{
    __shared__ __align__(16) __bf16 As[3][8192];   // [buf][128 r x 64], XOR-swz slots
    __shared__ __align__(16) __bf16 Bs[3][4096];   // [buf][64 r x 64], XOR-swz
    const int t = threadIdx.x;
    const int lane = t & 63, w = t >> 6;
    const int li = lane & 15, g = lane >> 4;
    const int wr = w >> 1, wc = w & 1;
    const int sw7 = li & 7;
    const int bid = (blockIdx.x & 7) * 64 + (blockIdx.x >> 3);
    const int m0 = (bid >> 4) << 7;   // 32 m-tiles
    const int n0 = (bid & 15) << 6;   // 16 n-tiles

#define PSTAGE(BUF, KT) do {                                                      \
    _Pragma("unroll")                                                             \
    for (int c_ = 0; c_ < 4; ++c_) {                                              \
        const int row_ = c_ * 32 + (t >> 3);                                      \
        async_copy16(A + (size_t)(m0 + row_) * 1024 + ((KT) << 6)                 \
                       + (((t & 7) ^ (row_ & 7)) << 3),                           \
                     &As[BUF][0] + c_ * 2048 + t * 8);                            \
    }                                                                             \
    _Pragma("unroll")                                                             \
    for (int c_ = 0; c_ < 2; ++c_) {                                              \
        const int row_ = c_ * 32 + (t >> 3);                                      \
        async_copy16(Bm + (size_t)(n0 + row_) * 1024 + ((KT) << 6)                \
                       + (((t & 7) ^ (row_ & 7)) << 3),                           \
                     &Bs[BUF][0] + c_ * 2048 + t * 8);                            \
    }                                                                             \
} while (0)

    f32x4 acc[4][2] = {};

    PSTAGE(0, 0);
    int cur = 0;
    for (int kt = 0; kt < 16; ++kt) {
        int nxt = cur + 1; if (nxt == 3) nxt = 0;
        if (kt < 15) {
            PSTAGE(nxt, kt + 1);
            VM6();
        } else {
            asm volatile("s_waitcnt vmcnt(0)" ::: "memory");
        }
        __builtin_amdgcn_sched_barrier(0);
        __builtin_amdgcn_s_barrier();
        __builtin_amdgcn_sched_barrier(0);

        bf16x8 af[4][2], bf[2][2];
#pragma unroll
        for (int mi = 0; mi < 4; ++mi) {
            const int ra = wr * 64 + mi * 16 + li;
#pragma unroll
            for (int kk = 0; kk < 2; ++kk)
                af[mi][kk] = *reinterpret_cast<const bf16x8*>(
                    (char*)&As[cur][0] + ra * 128 + (((kk * 4 + g) ^ sw7) << 4));
        }
#pragma unroll
        for (int ni = 0; ni < 2; ++ni) {
            const int rb = wc * 32 + ni * 16 + li;
#pragma unroll
            for (int kk = 0; kk < 2; ++kk)
                bf[ni][kk] = *reinterpret_cast<const bf16x8*>(
                    (char*)&Bs[cur][0] + rb * 128 + (((kk * 4 + g) ^ sw7) << 4));
        }
        __builtin_amdgcn_s_setprio(1);
#pragma unroll
        for (int mi = 0; mi < 4; ++mi)
#pragma unroll
            for (int ni = 0; ni < 2; ++ni) {
                f32x4 c_ = acc[mi][ni];
                c_ = MFMA16(af[mi][0], bf[ni][0], c_);
                c_ = MFMA16(af[mi][1], bf[ni][1], c_);
                acc[mi][ni] = c_;
            }
        __builtin_amdgcn_s_setprio(0);
        cur = nxt;
    }
#undef PSTAGE

#pragma unroll
    for (int mi = 0; mi < 4; ++mi) {
#pragma unroll
        for (int ni = 0; ni < 2; ++ni) {
            const int n = n0 + wc * 32 + ni * 16 + li;
            const float bv = bias[n];
#pragma unroll
            for (int r = 0; r < 4; ++r) {
                const int m = m0 + wr * 64 + mi * 16 + g * 4 + r;
                outf[(size_t)m * 1024 + n] = acc[mi][ni][r] + bv;
            }
        }
    }
}

// ------- flash attention, causal: 8 waves x 16q, QUAD-buffer counted-vmcnt --------
// (r12-exact, proven 54us). q:[BH,2048,64] (scale*log2e prefolded),
// k:[BH,2048,64], vT:[BH,64,2048] bf16.
__global__ __launch_bounds__(512) void attn_k(
    const __bf16* __restrict__ qg, const __bf16* __restrict__ kg,
    const __bf16* __restrict__ vtg, const int* __restrict__ mflag,
    const int* __restrict__ mask, __bf16* __restrict__ ao)
{
    __shared__ __align__(16) __bf16 Ks[4][4096];   // [64 keys][64 d], 16B-slot XOR-swz
    __shared__ __align__(16) __bf16 Vs[4][4096];   // [64 d][64 keys], XOR-swz
    __shared__ __align__(16) __bf16 Ps[8][1024];   // per-wave P [16 q][64 keys], XOR-swz
    const int t = threadIdx.x;
    const int w = t >> 6, lane = t & 63;
    const int li = lane & 15, g = lane >> 4;
    const int xcd = blockIdx.x & 7;
    const int idx = blockIdx.x >> 3;          // 0..63
    const int hg  = xcd * 4 + (idx & 3);      // 0..31
    const int q_  = idx >> 2;                 // 0..15
    const int band = (q_ < 8) ? (15 - q_) : (q_ - 8);
    const int bI = hg >> 4, hI = hg & 15;
    const int iq = band * 128 + w * 16 + li;  // this lane's query row
    const int mydiag = 2 * band + (w >> 2);   // this wave's last 64-key tile
    const int ktmax = 2 * band + 1;           // block's last staged tile (>=1)
    const int rowt = 2 * band + (w >> 2);     // wave's 64-row mask tile
    const size_t hoff = (size_t)hg * (2048 * 64);
    const __bf16* qh = qg + hoff;
    const __bf16* kh = kg + hoff;
    const __bf16* vh = vtg + hoff;
    char* pw = (char*)&Ps[w][0];
    const int sw7 = li & 7;

    // Q B-operand frags: qf[half] = Q[iq][32*half + 8g + j]
    bf16x8 qf[2];
#pragma unroll
    for (int half = 0; half < 2; ++half)
        qf[half] = *reinterpret_cast<const bf16x8*>(&qh[(size_t)iq * 64 + half * 32 + g * 8]);

    f32x4 o[4] = {};                          // O[d=16df+4g+r][q=li]
    float mrun = -1e30f, lrun = 0.0f;         // lrun = per-lane partial (own keys)

    // stage one 64-key tile into buffer BUF: K 8KB + V 8KB, 512 thr x 16B each
#define STAGE(BUF, KT) do {                                                       \
    const int p_ = t * 16;                                                        \
    const int row_ = p_ >> 7, sl_ = (p_ >> 4) & 7;                                \
    const int gc_ = (sl_ ^ (row_ & 7)) << 3;                                      \
    async_copy16(kh + (size_t)(((KT) << 6) + row_) * 64 + gc_,                    \
                 (__bf16*)((char*)(&Ks[0][0]) + (BUF) * 8192 + p_));              \
    async_copy16(vh + (size_t)row_ * 2048 + ((KT) << 6) + gc_,                    \
                 (__bf16*)((char*)(&Vs[0][0]) + (BUF) * 8192 + p_));              \
} while (0)

    // prologue: tiles 0,1 in flight; vmcnt(2) -> tile 0 landed; barrier.
    STAGE(0, 0);
    STAGE(1, 1);
    VM2();
    __builtin_amdgcn_s_barrier();

    int cur = 0;
    for (int kt = 0; kt <= ktmax; ++kt) {
        // T4: stage 2 ahead into buffer (cur+2)&3 (tile kt-2's buffer -- all its
        // readers finished before barrier kt-1, already crossed). Counted wait
        // ensures tile kt+1 landed; tile kt was ensured last interval.
        if (kt + 2 <= ktmax) {
            STAGE((cur + 2) & 3, kt + 2);
            VM2();
        } else {
            asm volatile("s_waitcnt vmcnt(0)" ::: "memory");   // tail only
        }
        __builtin_amdgcn_sched_barrier(0);
        __builtin_amdgcn_s_barrier();
        __builtin_amdgcn_sched_barrier(0);
        if (kt <= mydiag) {
            const char* kb = (char*)&Ks[0][0] + cur * 8192;
            const char* vb = (char*)&Vs[0][0] + cur * 8192;
            // ---- S^T = K Q^T : s[kb_][r] = S[key = 64kt+16kb_+4g+r][q = li]
            f32x4 s[4] = {};
            __builtin_amdgcn_s_setprio(1);
#pragma unroll
            for (int kb_ = 0; kb_ < 4; ++kb_) {
                const int row = kb_ * 16 + li;
#pragma unroll
                for (int half = 0; half < 2; ++half) {
                    bf16x8 kf = *reinterpret_cast<const bf16x8*>(
                        kb + row * 128 + (((half * 4 + g) ^ sw7) << 4));
                    s[kb_] = MFMA16(kf, qf[half], s[kb_]);
                }
            }
            __builtin_amdgcn_s_setprio(0);
            // ---- causal / padding mask (diag tile only; pad path never taken here)
            const bool pflag = (mflag[(bI * 32 + rowt) * 32 + kt] == 0);
            if (pflag || kt == mydiag) {
                const int jb = kt * 64;
#pragma unroll
                for (int kb_ = 0; kb_ < 4; ++kb_)
#pragma unroll
                    for (int r = 0; r < 4; ++r) {
                        const int j0 = jb + kb_ * 16 + 4 * g + r;
                        float v0 = s[kb_][r];
                        if (j0 > iq ||
                            (pflag && mask[((size_t)(bI * 2048 + iq)) * 2048 + j0] == 0))
                            v0 = -1e30f;
                        s[kb_][r] = v0;
                    }
            }
            // ---- online softmax, exp2 domain, defer-max (THR=8)
            float mt = fmaxf(fmaxf(s[0][0], s[0][1]), fmaxf(s[0][2], s[0][3]));
#pragma unroll
            for (int kb_ = 1; kb_ < 4; ++kb_)
                mt = fmaxf(mt, fmaxf(fmaxf(s[kb_][0], s[kb_][1]),
                                     fmaxf(s[kb_][2], s[kb_][3])));
            mt = fmaxf(mt, __shfl_xor(mt, 16));
            mt = fmaxf(mt, __shfl_xor(mt, 32));
            if (!__all(mt <= mrun + 8.0f)) {
                const float mn = fmaxf(mrun, mt);
                const float alpha = exp2f(mrun - mn);
#pragma unroll
                for (int df = 0; df < 4; ++df)
#pragma unroll
                    for (int r = 0; r < 4; ++r) o[df][r] *= alpha;
                lrun *= alpha;
                mrun = mn;
            }
#pragma unroll
            for (int kb_ = 0; kb_ < 4; ++kb_)
#pragma unroll
                for (int r = 0; r < 4; ++r) {
                    const float p = exp2f(s[kb_][r] - mrun);
                    s[kb_][r] = p;
                    lrun += p;
                }
            // ---- P -> per-wave LDS (swizzled), lands in PV B-operand layout
#pragma unroll
            for (int kb_ = 0; kb_ < 4; ++kb_) {
                const unsigned lo = packbf(s[kb_][0], s[kb_][1]);
                const unsigned hi = packbf(s[kb_][2], s[kb_][3]);
                *reinterpret_cast<uint2*>(
                    pw + li * 128 + (((2 * kb_ + (g >> 1)) ^ sw7) << 4) + ((g & 1) << 3)) =
                    make_uint2(lo, hi);
            }
            bf16x8 pb[2];
#pragma unroll
            for (int ks = 0; ks < 2; ++ks)
                pb[ks] = *reinterpret_cast<const bf16x8*>(
                    pw + li * 128 + (((4 * ks + g) ^ sw7) << 4));
            // ---- O += V^T P : A = Vt rows (d), 8 MFMA16
            __builtin_amdgcn_s_setprio(1);
#pragma unroll
            for (int df = 0; df < 4; ++df) {
                const int vrow = df * 16 + li;
#pragma unroll
                for (int ks = 0; ks < 2; ++ks) {
                    bf16x8 vf = *reinterpret_cast<const bf16x8*>(
                        vb + vrow * 128 + (((4 * ks + g) ^ sw7) << 4));
                    o[df] = MFMA16(vf, pb[ks], o[df]);
                }
            }
            __builtin_amdgcn_s_setprio(0);
        }
        cur = (cur + 1) & 3;
    }
#undef STAGE

    // ---- epilogue: finish lrun reduction, normalize, write
    lrun += __shfl_xor(lrun, 16);
    lrun += __shfl_xor(lrun, 32);
    const float inv = 1.0f / lrun;
    __bf16* aor = ao + ((size_t)(bI * 2048 + iq)) * 1024 + hI * 64 + g * 4;
#pragma unroll
    for (int df = 0; df < 4; ++df) {
        bf16x4 st;
#pragma unroll
        for (int r = 0; r < 4; ++r) st[r] = (__bf16)(o[df][r] * inv);
        *reinterpret_cast<bf16x4*>(&aor[df * 16]) = st;
    }
}

// ------------------------------- launch -----------------------------------------
extern "C" void kernel_launch(void* const* d_in, const int* in_sizes, int n_in,
                              void* d_out, int out_size, void* d_ws, size_t ws_size,
                              hipStream_t stream)
{
    const float* x      = (const float*)d_in[0];
    const int*   mask   = (const int*)d_in[1];
    const float* qkv_w  = (const float*)d_in[2];
    const float* qkv_b  = (const float*)d_in[3];
    const float* proj_w = (const float*)d_in[4];
    const float* proj_b = (const float*)d_in[5];
    float* out = (float*)d_out;

    char* ws = (char*)d_ws;
    __bf16* xb    = (__bf16*)(ws + 0);          // 4096x1024        8 MB
    __bf16* wqkv  = (__bf16*)(ws + 8388608);    // 3072x1024        6 MB
    __bf16* wproj = (__bf16*)(ws + 14680064);   // 1024x1024        2 MB
    __bf16* qg    = (__bf16*)(ws + 16777216);   // [32,2048,64]     8 MB
    __bf16* kg    = (__bf16*)(ws + 25165824);   // [32,2048,64]     8 MB
    __bf16* vtg   = (__bf16*)(ws + 33554432);   // [32,64,2048]     8 MB
    __bf16* ao    = (__bf16*)(ws + 41943040);   // 4096x1024        8 MB
    int*    mflag = (int*)(ws + 50331648);      // [2,32,32]        4 KB

    prep_k<<<10240, 256, 0, stream>>>(x, xb, qkv_w, wqkv, proj_w, wproj, mask, mflag);
    gemm_qkv8_k<<<192, 512, 0, stream>>>(xb, wqkv, qkv_b, qg, kg, vtg);
    attn_k<<<512, 512, 0, stream>>>(qg, kg, vtg, mflag, mask, ao);
    gemm_proj_k<<<512, 256, 0, stream>>>(ao, wproj, proj_b, out);
}

// Round 15
// 118.930 us; speedup vs baseline: 1.1751x; 1.0010x over previous
//
#include <hip/hip_runtime.h>
#include <hip/hip_bf16.h>

// UnifiedAttention: x->QKV gemm -> causal MHA (H=16,D=64) -> proj gemm
// B=2, N=2048, C=1024. bf16 MFMA with fp32 accum throughout.

typedef __bf16 bf16x8 __attribute__((ext_vector_type(8)));
typedef __bf16 bf16x4 __attribute__((ext_vector_type(4)));
typedef __bf16 bf16x2 __attribute__((ext_vector_type(2)));
typedef float  f32x4  __attribute__((ext_vector_type(4)));
typedef float  f32x16 __attribute__((ext_vector_type(16)));
typedef int    i32x4  __attribute__((ext_vector_type(4)));

#define MFMA16(a, b, c) __builtin_amdgcn_mfma_f32_16x16x32_bf16((a), (b), (c), 0, 0, 0)

__device__ __forceinline__ void async_copy16(const __bf16* g, __bf16* l) {
    __builtin_amdgcn_global_load_lds(
        (const __attribute__((address_space(1))) void*)g,
        (__attribute__((address_space(3))) void*)l,
        16, 0, 0);
}

__device__ __forceinline__ unsigned packbf(float a, float b) {
    union { bf16x2 v; unsigned u; } un;
    un.v[0] = (__bf16)a; un.v[1] = (__bf16)b;
    return un.u;
}

// -------- merged prep: fp32->bf16 conversions (blocks 0..8191) + mask reduce ------
// conv: 2097152 quads = 8192 blocks x 256 (x 1048576, qkv_w 786432, proj_w 262144).
// mask: blocks 8192..10239 -> 64x64 tile all-ones flags [2,32,32].
__global__ void prep_k(const float* __restrict__ x, __bf16* __restrict__ xb,
                       const float* __restrict__ qkvw, __bf16* __restrict__ wqkv,
                       const float* __restrict__ projw, __bf16* __restrict__ wproj,
                       const int* __restrict__ mask, int* __restrict__ mflag)
{
    if (blockIdx.x < 8192) {
        const int i = blockIdx.x * 256 + threadIdx.x;   // quad index
        const float* src; __bf16* dst; int j;
        if (i < 1048576)            { src = x;     dst = xb;    j = i; }
        else if (i < 1835008)       { src = qkvw;  dst = wqkv;  j = i - 1048576; }
        else                        { src = projw; dst = wproj; j = i - 1835008; }
        float4 v = reinterpret_cast<const float4*>(src)[j];
        bf16x4 o;
        o[0] = (__bf16)v.x; o[1] = (__bf16)v.y; o[2] = (__bf16)v.z; o[3] = (__bf16)v.w;
        reinterpret_cast<bf16x4*>(dst)[j] = o;
    } else {
        __shared__ int ok;
        const int t = threadIdx.x;
        if (t == 0) ok = 1;
        __syncthreads();
        const int bb = blockIdx.x - 8192;
        const int jt = bb & 31;
        const int it = (bb >> 5) & 31;
        const int b  = bb >> 10;
        bool all1 = true;
#pragma unroll
        for (int c = 0; c < 4; ++c) {
            const int row = c * 16 + (t >> 4);
            const int col = (t & 15) * 4;
            const int4 v = *reinterpret_cast<const int4*>(
                &mask[((size_t)(b * 2048 + it * 64 + row)) * 2048 + jt * 64 + col]);
            all1 = all1 && v.x && v.y && v.z && v.w;
        }
        if (!all1) ok = 0;
        __syncthreads();
        if (t == 0) mflag[(b * 32 + it) * 32 + jt] = ok;
    }
}

// ============ 8-phase 256x256 QKV GEMM (T1+T2+T3+T4+T5), K=1024 =================
#define BAR() asm volatile("s_barrier" ::: "memory")
#define VM2() asm volatile("s_waitcnt vmcnt(2)" ::: "memory")
#define VM6() asm volatile("s_waitcnt vmcnt(6)" ::: "memory")

__global__ __launch_bounds__(512, 2) void gemm_qkv8_k(
    const __bf16* __restrict__ A, const __bf16* __restrict__ Bm,
    const float* __restrict__ bias,
    __bf16* __restrict__ qg, __bf16* __restrict__ kg, __bf16* __restrict__ vtg)
{
    __shared__ __align__(16) __bf16 As[2][16384];   // [buf][256 rows x 64]
    __shared__ __align__(16) __bf16 Bs[2][16384];

    const int t = threadIdx.x;
    const int lane = t & 63;
    const int w = t >> 6;
    const int wr = w >> 2, wc = w & 3;
    const int li = lane & 15, g = lane >> 4;

    // XCD-aware bijective swizzle (grid=192, 192%8==0, 24 blocks per XCD)
    const int bid = (blockIdx.x & 7) * 24 + (blockIdx.x >> 3);
    const int m0 = (bid / 12) << 8;     // N tiles = 3072/256 = 12
    const int n0 = (bid % 12) << 8;

    const int srow = t >> 3;
    const int scol = ((t & 7) ^ (srow & 7)) << 3;
    const __bf16* pA = A  + (size_t)(m0 + srow) * 1024 + scol;
    const __bf16* pB = Bm + (size_t)(n0 + srow) * 1024 + scol;
    __bf16* dA = &As[0][0] + t * 8;
    __bf16* dB = &Bs[0][0] + t * 8;

#define STAGE_A(BB, T, HH) do {                                                   \
    const size_t ro_ = (size_t)((HH) * 128) * 1024 + (size_t)(T) * 64;            \
    async_copy16(pA + ro_,         dA + (BB) * 16384 + (HH) * 8192);              \
    async_copy16(pA + ro_ + 65536, dA + (BB) * 16384 + (HH) * 8192 + 4096);       \
  } while (0)
#define STAGE_B(BB, T, HH) do {                                                   \
    const size_t ro_ = (size_t)((HH) * 128) * 1024 + (size_t)(T) * 64;            \
    async_copy16(pB + ro_,         dB + (BB) * 16384 + (HH) * 8192);              \
    async_copy16(pB + ro_ + 65536, dB + (BB) * 16384 + (HH) * 8192 + 4096);       \
  } while (0)

    const int aoff0 = ((0 + g) ^ (li & 7)) << 3;
    const int aoff1 = ((4 + g) ^ (li & 7)) << 3;
    const int abase = (wr * 128 + li) * 64;
    const int bbase = (wc * 64 + li) * 64;

    f32x4 acc[8][4] = {};
    bf16x8 a[4][2], b[2][2][2];

#define READ_A(BB, MH) do { _Pragma("unroll")                                     \
    for (int mi2 = 0; mi2 < 4; ++mi2) {                                           \
      const __bf16* p_ = &As[BB][abase + ((MH) * 4 + mi2) * 1024];                \
      a[mi2][0] = *reinterpret_cast<const bf16x8*>(p_ + aoff0);                   \
      a[mi2][1] = *reinterpret_cast<const bf16x8*>(p_ + aoff1); } } while (0)
#define READ_B(BB, NH) do { _Pragma("unroll")                                     \
    for (int ni2 = 0; ni2 < 2; ++ni2) {                                           \
      const __bf16* p_ = &Bs[BB][bbase + ((NH) * 2 + ni2) * 1024];                \
      b[NH][ni2][0] = *reinterpret_cast<const bf16x8*>(p_ + aoff0);               \
      b[NH][ni2][1] = *reinterpret_cast<const bf16x8*>(p_ + aoff1); } } while (0)
#define MFMA_QUAD(MH, NH) do {                                                    \
    __builtin_amdgcn_s_setprio(1);                                                \
    _Pragma("unroll") for (int mi2 = 0; mi2 < 4; ++mi2)                           \
    _Pragma("unroll") for (int ni2 = 0; ni2 < 2; ++ni2) {                         \
      f32x4 c_ = acc[(MH) * 4 + mi2][(NH) * 2 + ni2];                             \
      c_ = MFMA16(a[mi2][0], b[NH][ni2][0], c_);                                  \
      c_ = MFMA16(a[mi2][1], b[NH][ni2][1], c_);                                  \
      acc[(MH) * 4 + mi2][(NH) * 2 + ni2] = c_; }                                 \
    __builtin_amdgcn_s_setprio(0); } while (0)

#define KTILE(BB, T) do {                                                         \
    const int Tn_  = ((T) + 1 < 16) ? (T) + 1 : 15;                               \
    const int Tn2_ = ((T) + 2 < 16) ? (T) + 2 : 15;                               \
    STAGE_A((BB) ^ 1, Tn_, 1);                                                    \
    READ_A(BB, 0); READ_B(BB, 0);                                                 \
    BAR(); MFMA_QUAD(0, 0); BAR();                                                \
    STAGE_B((BB) ^ 1, Tn_, 0);                                                    \
    READ_B(BB, 1);                                                                \
    BAR(); MFMA_QUAD(0, 1); BAR();                                                \
    STAGE_B((BB) ^ 1, Tn_, 1);                                                    \
    READ_A(BB, 1);                                                                \
    BAR(); MFMA_QUAD(1, 0); BAR();                                                \
    STAGE_A((BB), Tn2_, 0);                                                       \
    VM2(); BAR(); MFMA_QUAD(1, 1); BAR();                                         \
  } while (0)

    STAGE_A(0, 0, 0); STAGE_A(0, 0, 1);
    STAGE_B(0, 0, 0); STAGE_B(0, 0, 1);
    STAGE_A(1, 1, 0);
    VM2(); BAR();

#pragma unroll 1
    for (int jj = 0; jj < 8; ++jj) {
        KTILE(0, 2 * jj);
        KTILE(1, 2 * jj + 1);
    }

    // ---- epilogue: scatter into q (scaled by 0.125*log2e for exp2 softmax) / k / vT
    const int nbase = n0 + wc * 64;
    const int s = nbase >> 10;
    const int headg = (m0 >> 11) * 16 + ((nbase & 1023) >> 6);
    const int mrow = (m0 & 2047) + wr * 128 + g * 4;
    float bv[4];
#pragma unroll
    for (int ni = 0; ni < 4; ++ni) bv[ni] = bias[nbase + ni * 16 + li];

    if (s == 2) {
#pragma unroll
        for (int mi = 0; mi < 8; ++mi) {
#pragma unroll
            for (int ni = 0; ni < 4; ++ni) {
                bf16x4 st;
#pragma unroll
                for (int r = 0; r < 4; ++r) st[r] = (__bf16)(acc[mi][ni][r] + bv[ni]);
                *reinterpret_cast<bf16x4*>(
                    &vtg[((size_t)(headg * 64) + ni * 16 + li) * 2048 + mrow + mi * 16]) = st;
            }
        }
    } else {
        __bf16* og = (s == 0) ? qg : kg;
        const float sc = (s == 0) ? 0.18033688f : 1.0f;   // 0.125 * log2(e)
#pragma unroll
        for (int mi = 0; mi < 8; ++mi) {
#pragma unroll
            for (int r = 0; r < 4; ++r) {
                __bf16* rp = og + ((size_t)headg * 2048 + mrow + mi * 16 + r) * 64;
#pragma unroll
                for (int ni = 0; ni < 4; ++ni)
                    rp[ni * 16 + li] = (__bf16)((acc[mi][ni][r] + bv[ni]) * sc);
            }
        }
    }
#undef KTILE
#undef MFMA_QUAD
#undef READ_A
#undef READ_B
#undef STAGE_A
#undef STAGE_B
}

// ------- proj GEMM: 128x64 tile, BK=64, 3-buffer counted-vmcnt (distance-1) -------
__global__ __launch_bounds__(256) void gemm_proj_k(
    const __bf16* __restrict__ A, const __bf16* __restrict__ Bm,
    const float* __restrict__ bias, float* __restrict__ outf)
{
    __shared__ __align__(16) __bf16 As[3][8192];   // [buf][128 r x 64], XOR-swz slots
    __shared__ __align__(16) __bf16 Bs[3][4096];   // [buf][64 r x 64], XOR-swz
    const int t = threadIdx.x;
    const int lane = t & 63, w = t >> 6;
    const int li = lane & 15, g = lane >> 4;
    const int wr = w >> 1, wc = w & 1;
    const int sw7 = li & 7;
    const int bid = (blockIdx.x & 7) * 64 + (blockIdx.x >> 3);
    const int m0 = (bid >> 4) << 7;   // 32 m-tiles
    const int n0 = (bid & 15) << 6;   // 16 n-tiles

#define PSTAGE(BUF, KT) do {                                                      \
    _Pragma("unroll")                                                             \
    for (int c_ = 0; c_ < 4; ++c_) {                                              \
        const int row_ = c_ * 32 + (t >> 3);                                      \
        async_copy16(A + (size_t)(m0 + row_) * 1024 + ((KT) << 6)                 \
                       + (((t & 7) ^ (row_ & 7)) << 3),                           \
                     &As[BUF][0] + c_ * 2048 + t * 8);                            \
    }                                                                             \
    _Pragma("unroll")                                                             \
    for (int c_ = 0; c_ < 2; ++c_) {                                              \
        const int row_ = c_ * 32 + (t >> 3);                                      \
        async_copy16(Bm + (size_t)(n0 + row_) * 1024 + ((KT) << 6)                \
                       + (((t & 7) ^ (row_ & 7)) << 3),                           \
                     &Bs[BUF][0] + c_ * 2048 + t * 8);                            \
    }                                                                             \
} while (0)

    f32x4 acc[4][2] = {};

    PSTAGE(0, 0);
    int cur = 0;
    for (int kt = 0; kt < 16; ++kt) {
        int nxt = cur + 1; if (nxt == 3) nxt = 0;
        if (kt < 15) {
            PSTAGE(nxt, kt + 1);
            VM6();
        } else {
            asm volatile("s_waitcnt vmcnt(0)" ::: "memory");
        }
        __builtin_amdgcn_sched_barrier(0);
        __builtin_amdgcn_s_barrier();
        __builtin_amdgcn_sched_barrier(0);

        bf16x8 af[4][2], bf[2][2];
#pragma unroll
        for (int mi = 0; mi < 4; ++mi) {
            const int ra = wr * 64 + mi * 16 + li;
#pragma unroll
            for (int kk = 0; kk < 2; ++kk)
                af[mi][kk] = *reinterpret_cast<const bf16x8*>(
                    (char*)&As[cur][0] + ra * 128 + (((kk * 4 + g) ^ sw7) << 4));
        }
#pragma unroll
        for (int ni = 0; ni < 2; ++ni) {
            const int rb = wc * 32 + ni * 16 + li;
#pragma unroll
            for (int kk = 0; kk < 2; ++kk)
                bf[ni][kk] = *reinterpret_cast<const bf16x8*>(
                    (char*)&Bs[cur][0] + rb * 128 + (((kk * 4 + g) ^ sw7) << 4));
        }
        __builtin_amdgcn_s_setprio(1);
#pragma unroll
        for (int mi = 0; mi < 4; ++mi)
#pragma unroll
            for (int ni = 0; ni < 2; ++ni) {
                f32x4 c_ = acc[mi][ni];
                c_ = MFMA16(af[mi][0], bf[ni][0], c_);
                c_ = MFMA16(af[mi][1], bf[ni][1], c_);
                acc[mi][ni] = c_;
            }
        __builtin_amdgcn_s_setprio(0);
        cur = nxt;
    }
#undef PSTAGE

#pragma unroll
    for (int mi = 0; mi < 4; ++mi) {
#pragma unroll
        for (int ni = 0; ni < 2; ++ni) {
            const int n = n0 + wc * 32 + ni * 16 + li;
            const float bv = bias[n];
#pragma unroll
            for (int r = 0; r < 4; ++r) {
                const int m = m0 + wr * 64 + mi * 16 + g * 4 + r;
                outf[(size_t)m * 1024 + n] = acc[mi][ni][r] + bv;
            }
        }
    }
}

// ------- flash attention, causal: 8 waves x 16q, QUAD-buffer counted-vmcnt --------
// (r12-exact, proven 54us). q:[BH,2048,64] (scale*log2e prefolded),
// k:[BH,2048,64], vT:[BH,64,2048] bf16.
__global__ __launch_bounds__(512) void attn_k(
    const __bf16* __restrict__ qg, const __bf16* __restrict__ kg,
    const __bf16* __restrict__ vtg, const int* __restrict__ mflag,
    const int* __restrict__ mask, __bf16* __restrict__ ao)
{
    __shared__ __align__(16) __bf16 Ks[4][4096];   // [64 keys][64 d], 16B-slot XOR-swz
    __shared__ __align__(16) __bf16 Vs[4][4096];   // [64 d][64 keys], XOR-swz
    __shared__ __align__(16) __bf16 Ps[8][1024];   // per-wave P [16 q][64 keys], XOR-swz
    const int t = threadIdx.x;
    const int w = t >> 6, lane = t & 63;
    const int li = lane & 15, g = lane >> 4;
    const int xcd = blockIdx.x & 7;
    const int idx = blockIdx.x >> 3;          // 0..63
    const int hg  = xcd * 4 + (idx & 3);      // 0..31
    const int q_  = idx >> 2;                 // 0..15
    const int band = (q_ < 8) ? (15 - q_) : (q_ - 8);
    const int bI = hg >> 4, hI = hg & 15;
    const int iq = band * 128 + w * 16 + li;  // this lane's query row
    const int mydiag = 2 * band + (w >> 2);   // this wave's last 64-key tile
    const int ktmax = 2 * band + 1;           // block's last staged tile (>=1)
    const int rowt = 2 * band + (w >> 2);     // wave's 64-row mask tile
    const size_t hoff = (size_t)hg * (2048 * 64);
    const __bf16* qh = qg + hoff;
    const __bf16* kh = kg + hoff;
    const __bf16* vh = vtg + hoff;
    char* pw = (char*)&Ps[w][0];
    const int sw7 = li & 7;

    // Q B-operand frags: qf[half] = Q[iq][32*half + 8g + j]
    bf16x8 qf[2];
#pragma unroll
    for (int half = 0; half < 2; ++half)
        qf[half] = *reinterpret_cast<const bf16x8*>(&qh[(size_t)iq * 64 + half * 32 + g * 8]);

    f32x4 o[4] = {};                          // O[d=16df+4g+r][q=li]
    float mrun = -1e30f, lrun = 0.0f;         // lrun = per-lane partial (own keys)

    // stage one 64-key tile into buffer BUF: K 8KB + V 8KB, 512 thr x 16B each
#define STAGE(BUF, KT) do {                                                       \
    const int p_ = t * 16;                                                        \
    const int row_ = p_ >> 7, sl_ = (p_ >> 4) & 7;                                \
    const int gc_ = (sl_ ^ (row_ & 7)) << 3;                                      \
    async_copy16(kh + (size_t)(((KT) << 6) + row_) * 64 + gc_,                    \
                 (__bf16*)((char*)(&Ks[0][0]) + (BUF) * 8192 + p_));              \
    async_copy16(vh + (size_t)row_ * 2048 + ((KT) << 6) + gc_,                    \
                 (__bf16*)((char*)(&Vs[0][0]) + (BUF) * 8192 + p_));              \
} while (0)

    // prologue: tiles 0,1 in flight; vmcnt(2) -> tile 0 landed; barrier.
    STAGE(0, 0);
    STAGE(1, 1);
    VM2();
    __builtin_amdgcn_s_barrier();

    int cur = 0;
    for (int kt = 0; kt <= ktmax; ++kt) {
        // T4: stage 2 ahead into buffer (cur+2)&3 (tile kt-2's buffer -- all its
        // readers finished before barrier kt-1, already crossed). Counted wait
        // ensures tile kt+1 landed; tile kt was ensured last interval.
        if (kt + 2 <= ktmax) {
            STAGE((cur + 2) & 3, kt + 2);
            VM2();
        } else {
            asm volatile("s_waitcnt vmcnt(0)" ::: "memory");   // tail only
        }
        __builtin_amdgcn_sched_barrier(0);
        __builtin_amdgcn_s_barrier();
        __builtin_amdgcn_sched_barrier(0);
        if (kt <= mydiag) {
            const char* kb = (char*)&Ks[0][0] + cur * 8192;
            const char* vb = (char*)&Vs[0][0] + cur * 8192;
            // ---- S^T = K Q^T : s[kb_][r] = S[key = 64kt+16kb_+4g+r][q = li]
            f32x4 s[4] = {};
            __builtin_amdgcn_s_setprio(1);
#pragma unroll
            for (int kb_ = 0; kb_ < 4; ++kb_) {
                const int row = kb_ * 16 + li;
#pragma unroll
                for (int half = 0; half < 2; ++half) {
                    bf16x8 kf = *reinterpret_cast<const bf16x8*>(
                        kb + row * 128 + (((half * 4 + g) ^ sw7) << 4));
                    s[kb_] = MFMA16(kf, qf[half], s[kb_]);
                }
            }
            __builtin_amdgcn_s_setprio(0);
            // ---- causal / padding mask (diag tile only; pad path never taken here)
            const bool pflag = (mflag[(bI * 32 + rowt) * 32 + kt] == 0);
            if (pflag || kt == mydiag) {
                const int jb = kt * 64;
#pragma unroll
                for (int kb_ = 0; kb_ < 4; ++kb_)
#pragma unroll
                    for (int r = 0; r < 4; ++r) {
                        const int j0 = jb + kb_ * 16 + 4 * g + r;
                        float v0 = s[kb_][r];
                        if (j0 > iq ||
                            (pflag && mask[((size_t)(bI * 2048 + iq)) * 2048 + j0] == 0))
                            v0 = -1e30f;
                        s[kb_][r] = v0;
                    }
            }
            // ---- online softmax, exp2 domain, defer-max (THR=8)
            float mt = fmaxf(fmaxf(s[0][0], s[0][1]), fmaxf(s[0][2], s[0][3]));
#pragma unroll
            for (int kb_ = 1; kb_ < 4; ++kb_)
                mt = fmaxf(mt, fmaxf(fmaxf(s[kb_][0], s[kb_][1]),
                                     fmaxf(s[kb_][2], s[kb_][3])));
            mt = fmaxf(mt, __shfl_xor(mt, 16));
            mt = fmaxf(mt, __shfl_xor(mt, 32));
            if (!__all(mt <= mrun + 8.0f)) {
                const float mn = fmaxf(mrun, mt);
                const float alpha = exp2f(mrun - mn);
#pragma unroll
                for (int df = 0; df < 4; ++df)
#pragma unroll
                    for (int r = 0; r < 4; ++r) o[df][r] *= alpha;
                lrun *= alpha;
                mrun = mn;
            }
#pragma unroll
            for (int kb_ = 0; kb_ < 4; ++kb_)
#pragma unroll
                for (int r = 0; r < 4; ++r) {
                    const float p = exp2f(s[kb_][r] - mrun);
                    s[kb_][r] = p;
                    lrun += p;
                }
            // ---- P -> per-wave LDS (swizzled), lands in PV B-operand layout
#pragma unroll
            for (int kb_ = 0; kb_ < 4; ++kb_) {
                const unsigned lo = packbf(s[kb_][0], s[kb_][1]);
                const unsigned hi = packbf(s[kb_][2], s[kb_][3]);
                *reinterpret_cast<uint2*>(
                    pw + li * 128 + (((2 * kb_ + (g >> 1)) ^ sw7) << 4) + ((g & 1) << 3)) =
                    make_uint2(lo, hi);
            }
            bf16x8 pb[2];
#pragma unroll
            for (int ks = 0; ks < 2; ++ks)
                pb[ks] = *reinterpret_cast<const bf16x8*>(
                    pw + li * 128 + (((4 * ks + g) ^ sw7) << 4));
            // ---- O += V^T P : A = Vt rows (d), 8 MFMA16
            __builtin_amdgcn_s_setprio(1);
#pragma unroll
            for (int df = 0; df < 4; ++df) {
                const int vrow = df * 16 + li;
#pragma unroll
                for (int ks = 0; ks < 2; ++ks) {
                    bf16x8 vf = *reinterpret_cast<const bf16x8*>(
                        vb + vrow * 128 + (((4 * ks + g) ^ sw7) << 4));
                    o[df] = MFMA16(vf, pb[ks], o[df]);
                }
            }
            __builtin_amdgcn_s_setprio(0);
        }
        cur = (cur + 1) & 3;
    }
#undef STAGE

    // ---- epilogue: finish lrun reduction, normalize, write
    lrun += __shfl_xor(lrun, 16);
    lrun += __shfl_xor(lrun, 32);
    const float inv = 1.0f / lrun;
    __bf16* aor = ao + ((size_t)(bI * 2048 + iq)) * 1024 + hI * 64 + g * 4;
#pragma unroll
    for (int df = 0; df < 4; ++df) {
        bf16x4 st;
#pragma unroll
        for (int r = 0; r < 4; ++r) st[r] = (__bf16)(o[df][r] * inv);
        *reinterpret_cast<bf16x4*>(&aor[df * 16]) = st;
    }
}

// ------------------------------- launch -----------------------------------------
extern "C" void kernel_launch(void* const* d_in, const int* in_sizes, int n_in,
                              void* d_out, int out_size, void* d_ws, size_t ws_size,
                              hipStream_t stream)
{
    const float* x      = (const float*)d_in[0];
    const int*   mask   = (const int*)d_in[1];
    const float* qkv_w  = (const float*)d_in[2];
    const float* qkv_b  = (const float*)d_in[3];
    const float* proj_w = (const float*)d_in[4];
    const float* proj_b = (const float*)d_in[5];
    float* out = (float*)d_out;

    char* ws = (char*)d_ws;
    __bf16* xb    = (__bf16*)(ws + 0);          // 4096x1024        8 MB
    __bf16* wqkv  = (__bf16*)(ws + 8388608);    // 3072x1024        6 MB
    __bf16* wproj = (__bf16*)(ws + 14680064);   // 1024x1024        2 MB
    __bf16* qg    = (__bf16*)(ws + 16777216);   // [32,2048,64]     8 MB
    __bf16* kg    = (__bf16*)(ws + 25165824);   // [32,2048,64]     8 MB
    __bf16* vtg   = (__bf16*)(ws + 33554432);   // [32,64,2048]     8 MB
    __bf16* ao    = (__bf16*)(ws + 41943040);   // 4096x1024        8 MB
    int*    mflag = (int*)(ws + 50331648);      // [2,32,32]        4 KB

    prep_k<<<10240, 256, 0, stream>>>(x, xb, qkv_w, wqkv, proj_w, wproj, mask, mflag);
    gemm_qkv8_k<<<192, 512, 0, stream>>>(xb, wqkv, qkv_b, qg, kg, vtg);
    attn_k<<<512, 512, 0, stream>>>(qg, kg, vtg, mflag, mask, ao);
    gemm_proj_k<<<512, 256, 0, stream>>>(ao, wproj, proj_b, out);
}

// Round 16
// 116.343 us; speedup vs baseline: 1.2012x; 1.0222x over previous
//
#include <hip/hip_runtime.h>
#include <hip/hip_bf16.h>

// UnifiedAttention: x->QKV gemm -> causal MHA (H=16,D=64) -> proj gemm
// B=2, N=2048, C=1024. bf16 MFMA with fp32 accum throughout.

typedef __bf16 bf16x8 __attribute__((ext_vector_type(8)));
typedef __bf16 bf16x4 __attribute__((ext_vector_type(4)));
typedef __bf16 bf16x2 __attribute__((ext_vector_type(2)));
typedef float  f32x4  __attribute__((ext_vector_type(4)));
typedef float  f32x16 __attribute__((ext_vector_type(16)));
typedef int    i32x4  __attribute__((ext_vector_type(4)));

#define MFMA16(a, b, c) __builtin_amdgcn_mfma_f32_16x16x32_bf16((a), (b), (c), 0, 0, 0)

__device__ __forceinline__ void async_copy16(const __bf16* g, __bf16* l) {
    __builtin_amdgcn_global_load_lds(
        (const __attribute__((address_space(1))) void*)g,
        (__attribute__((address_space(3))) void*)l,
        16, 0, 0);
}

__device__ __forceinline__ unsigned packbf(float a, float b) {
    union { bf16x2 v; unsigned u; } un;
    un.v[0] = (__bf16)a; un.v[1] = (__bf16)b;
    return un.u;
}

// -------- merged prep: fp32->bf16 conversions (blocks 0..8191) + mask reduce ------
__global__ void prep_k(const float* __restrict__ x, __bf16* __restrict__ xb,
                       const float* __restrict__ qkvw, __bf16* __restrict__ wqkv,
                       const float* __restrict__ projw, __bf16* __restrict__ wproj,
                       const int* __restrict__ mask, int* __restrict__ mflag)
{
    if (blockIdx.x < 8192) {
        const int i = blockIdx.x * 256 + threadIdx.x;   // quad index
        const float* src; __bf16* dst; int j;
        if (i < 1048576)            { src = x;     dst = xb;    j = i; }
        else if (i < 1835008)       { src = qkvw;  dst = wqkv;  j = i - 1048576; }
        else                        { src = projw; dst = wproj; j = i - 1835008; }
        float4 v = reinterpret_cast<const float4*>(src)[j];
        bf16x4 o;
        o[0] = (__bf16)v.x; o[1] = (__bf16)v.y; o[2] = (__bf16)v.z; o[3] = (__bf16)v.w;
        reinterpret_cast<bf16x4*>(dst)[j] = o;
    } else {
        __shared__ int ok;
        const int t = threadIdx.x;
        if (t == 0) ok = 1;
        __syncthreads();
        const int bb = blockIdx.x - 8192;
        const int jt = bb & 31;
        const int it = (bb >> 5) & 31;
        const int b  = bb >> 10;
        bool all1 = true;
#pragma unroll
        for (int c = 0; c < 4; ++c) {
            const int row = c * 16 + (t >> 4);
            const int col = (t & 15) * 4;
            const int4 v = *reinterpret_cast<const int4*>(
                &mask[((size_t)(b * 2048 + it * 64 + row)) * 2048 + jt * 64 + col]);
            all1 = all1 && v.x && v.y && v.z && v.w;
        }
        if (!all1) ok = 0;
        __syncthreads();
        if (t == 0) mflag[(b * 32 + it) * 32 + jt] = ok;
    }
}

// ====== 6-phase 256x192 QKV GEMM (T1+T2+T3+T4+T5), K=1024, grid 256 = 1/CU ======
// 8 waves (2M x 4N), per-wave C = 128x48 (acc[8][3]). BK=64.
// Staging per K-tile: A = 2 halves x 2 loads, B = 3 halves x 1 load (7 loads).
// Invariant: at each tile start, tile fully landed; next tile's A-h0 (2 loads)
// in flight. P6's vmcnt(2) leaves exactly T+2's A-h0 -> T+1 landed.
#define BAR() asm volatile("s_barrier" ::: "memory")
#define VM2() asm volatile("s_waitcnt vmcnt(2)" ::: "memory")
#define VM6() asm volatile("s_waitcnt vmcnt(6)" ::: "memory")

__global__ __launch_bounds__(512, 2) void gemm_qkv8_k(
    const __bf16* __restrict__ A, const __bf16* __restrict__ Bm,
    const float* __restrict__ bias,
    __bf16* __restrict__ qg, __bf16* __restrict__ kg, __bf16* __restrict__ vtg)
{
    __shared__ __align__(16) __bf16 As[2][16384];   // [buf][256 rows x 64]
    __shared__ __align__(16) __bf16 Bs[2][12288];   // [buf][192 rows x 64]

    const int t = threadIdx.x;
    const int lane = t & 63;
    const int w = t >> 6;
    const int wr = w >> 2, wc = w & 3;
    const int li = lane & 15, g = lane >> 4;

    // XCD-aware bijective swizzle (grid=256, 256%8==0, 32 blocks per XCD)
    const int bid = (blockIdx.x & 7) * 32 + (blockIdx.x >> 3);
    const int m0 = (bid >> 4) << 8;     // 16 m-tiles of 256
    const int n0 = (bid & 15) * 192;    // 16 n-tiles of 192

    const int srow = t >> 3;            // 0..63
    const int scol = ((t & 7) ^ (srow & 7)) << 3;
    const __bf16* pA = A  + (size_t)(m0 + srow) * 1024 + scol;
    const __bf16* pB = Bm + (size_t)(n0 + srow) * 1024 + scol;
    __bf16* dA = &As[0][0] + t * 8;
    __bf16* dB = &Bs[0][0] + t * 8;

// A half HH = rows HH*128..HH*128+127 (2 loads: 64 rows each)
#define STAGE_A(BB, T, HH) do {                                                   \
    const size_t ro_ = (size_t)((HH) * 128) * 1024 + (size_t)(T) * 64;            \
    async_copy16(pA + ro_,         dA + (BB) * 16384 + (HH) * 8192);              \
    async_copy16(pA + ro_ + 65536, dA + (BB) * 16384 + (HH) * 8192 + 4096);       \
  } while (0)
// B half HH = rows HH*64..HH*64+63 (1 load)
#define STAGE_B(BB, T, HH) do {                                                   \
    const size_t ro_ = (size_t)((HH) * 64) * 1024 + (size_t)(T) * 64;             \
    async_copy16(pB + ro_, dB + (BB) * 12288 + (HH) * 4096);                      \
  } while (0)

    const int aoff0 = ((0 + g) ^ (li & 7)) << 3;
    const int aoff1 = ((4 + g) ^ (li & 7)) << 3;
    const int abase = (wr * 128 + li) * 64;
    const int bbase = (wc * 48 + li) * 64;

    f32x4 acc[8][3] = {};
    bf16x8 a[4][2], b[3][2];

#define READ_A(BB, MH) do { _Pragma("unroll")                                     \
    for (int mi2 = 0; mi2 < 4; ++mi2) {                                           \
      const __bf16* p_ = &As[BB][abase + ((MH) * 4 + mi2) * 1024];                \
      a[mi2][0] = *reinterpret_cast<const bf16x8*>(p_ + aoff0);                   \
      a[mi2][1] = *reinterpret_cast<const bf16x8*>(p_ + aoff1); } } while (0)
#define READ_B(BB, NH) do {                                                       \
      const __bf16* p_ = &Bs[BB][bbase + (NH) * 1024];                            \
      b[NH][0] = *reinterpret_cast<const bf16x8*>(p_ + aoff0);                    \
      b[NH][1] = *reinterpret_cast<const bf16x8*>(p_ + aoff1); } while (0)
#define MFMA_QUAD(MH, NH) do {                                                    \
    __builtin_amdgcn_s_setprio(1);                                                \
    _Pragma("unroll") for (int mi2 = 0; mi2 < 4; ++mi2) {                         \
      f32x4 c_ = acc[(MH) * 4 + mi2][NH];                                         \
      c_ = MFMA16(a[mi2][0], b[NH][0], c_);                                       \
      c_ = MFMA16(a[mi2][1], b[NH][1], c_);                                       \
      acc[(MH) * 4 + mi2][NH] = c_; }                                             \
    __builtin_amdgcn_s_setprio(0); } while (0)

#define KTILE(BB, T) do {                                                         \
    const int Tn_  = ((T) + 1 < 16) ? (T) + 1 : 15;                               \
    const int Tn2_ = ((T) + 2 < 16) ? (T) + 2 : 15;                               \
    STAGE_A((BB) ^ 1, Tn_, 1);                                                    \
    READ_A(BB, 0); READ_B(BB, 0);                                                 \
    BAR(); MFMA_QUAD(0, 0); BAR();                                                \
    STAGE_B((BB) ^ 1, Tn_, 0);                                                    \
    READ_B(BB, 1);                                                                \
    BAR(); MFMA_QUAD(0, 1); BAR();                                                \
    STAGE_B((BB) ^ 1, Tn_, 1);                                                    \
    READ_B(BB, 2);                                                                \
    BAR(); MFMA_QUAD(0, 2); BAR();                                                \
    STAGE_B((BB) ^ 1, Tn_, 2);                                                    \
    READ_A(BB, 1);                                                                \
    BAR(); MFMA_QUAD(1, 0); BAR();                                                \
    STAGE_A((BB), Tn2_, 0);                                                       \
    BAR(); MFMA_QUAD(1, 1); BAR();                                                \
    VM2();                                                                        \
    BAR(); MFMA_QUAD(1, 2); BAR();                                                \
  } while (0)

    // prologue: tile0 (A h0,h1 + B h0..2 = 7 loads) + tile1 A-h0 (2); VM2 -> t0 landed.
    STAGE_A(0, 0, 0); STAGE_A(0, 0, 1);
    STAGE_B(0, 0, 0); STAGE_B(0, 0, 1); STAGE_B(0, 0, 2);
    STAGE_A(1, 1, 0);
    VM2(); BAR();

#pragma unroll 1
    for (int jj = 0; jj < 8; ++jj) {
        KTILE(0, 2 * jj);
        KTILE(1, 2 * jj + 1);
    }

    // ---- epilogue: scatter into q (scaled by 0.125*log2e) / k / vT, per 16-col frag
    const int mrow = (m0 & 2047) + wr * 128 + g * 4;   // + mi*16 + r
    const int bb16 = (m0 >> 11) * 16;
#pragma unroll
    for (int ni = 0; ni < 3; ++ni) {
        const int nfr = n0 + wc * 48 + ni * 16;        // frag base col (mult of 16)
        const int s = nfr >> 10;
        const int rem = nfr & 1023;
        const int headg = bb16 + (rem >> 6);
        const int d0 = rem & 63;
        const float bv = bias[nfr + li];
        if (s == 2) {
#pragma unroll
            for (int mi = 0; mi < 8; ++mi) {
                bf16x4 st;
#pragma unroll
                for (int r = 0; r < 4; ++r) st[r] = (__bf16)(acc[mi][ni][r] + bv);
                *reinterpret_cast<bf16x4*>(
                    &vtg[((size_t)(headg * 64) + d0 + li) * 2048 + mrow + mi * 16]) = st;
            }
        } else {
            __bf16* og = (s == 0) ? qg : kg;
            const float sc = (s == 0) ? 0.18033688f : 1.0f;   // 0.125 * log2(e)
#pragma unroll
            for (int mi = 0; mi < 8; ++mi) {
#pragma unroll
                for (int r = 0; r < 4; ++r) {
                    og[((size_t)headg * 2048 + mrow + mi * 16 + r) * 64 + d0 + li] =
                        (__bf16)((acc[mi][ni][r] + bv) * sc);
                }
            }
        }
    }
#undef KTILE
#undef MFMA_QUAD
#undef READ_A
#undef READ_B
#undef STAGE_A
#undef STAGE_B
}

// ------- proj GEMM: 128x64 tile, BK=64, 3-buffer counted-vmcnt (distance-1) -------
__global__ __launch_bounds__(256) void gemm_proj_k(
    const __bf16* __restrict__ A, const __bf16* __restrict__ Bm,
    const float* __restrict__ bias, float* __restrict__ outf)
{
    __shared__ __align__(16) __bf16 As[3][8192];   // [buf][128 r x 64], XOR-swz slots
    __shared__ __align__(16) __bf16 Bs[3][4096];   // [buf][64 r x 64], XOR-swz
    const int t = threadIdx.x;
    const int lane = t & 63, w = t >> 6;
    const int li = lane & 15, g = lane >> 4;
    const int wr = w >> 1, wc = w & 1;
    const int sw7 = li & 7;
    const int bid = (blockIdx.x & 7) * 64 + (blockIdx.x >> 3);
    const int m0 = (bid >> 4) << 7;   // 32 m-tiles
    const int n0 = (bid & 15) << 6;   // 16 n-tiles

#define PSTAGE(BUF, KT) do {                                                      \
    _Pragma("unroll")                                                             \
    for (int c_ = 0; c_ < 4; ++c_) {                                              \
        const int row_ = c_ * 32 + (t >> 3);                                      \
        async_copy16(A + (size_t)(m0 + row_) * 1024 + ((KT) << 6)                 \
                       + (((t & 7) ^ (row_ & 7)) << 3),                           \
                     &As[BUF][0] + c_ * 2048 + t * 8);                            \
    }                                                                             \
    _Pragma("unroll")                                                             \
    for (int c_ = 0; c_ < 2; ++c_) {                                              \
        const int row_ = c_ * 32 + (t >> 3);                                      \
        async_copy16(Bm + (size_t)(n0 + row_) * 1024 + ((KT) << 6)                \
                       + (((t & 7) ^ (row_ & 7)) << 3),                           \
                     &Bs[BUF][0] + c_ * 2048 + t * 8);                            \
    }                                                                             \
} while (0)

    f32x4 acc[4][2] = {};

    PSTAGE(0, 0);
    int cur = 0;
    for (int kt = 0; kt < 16; ++kt) {
        int nxt = cur + 1; if (nxt == 3) nxt = 0;
        if (kt < 15) {
            PSTAGE(nxt, kt + 1);
            VM6();
        } else {
            asm volatile("s_waitcnt vmcnt(0)" ::: "memory");
        }
        __builtin_amdgcn_sched_barrier(0);
        __builtin_amdgcn_s_barrier();
        __builtin_amdgcn_sched_barrier(0);

        bf16x8 af[4][2], bf[2][2];
#pragma unroll
        for (int mi = 0; mi < 4; ++mi) {
            const int ra = wr * 64 + mi * 16 + li;
#pragma unroll
            for (int kk = 0; kk < 2; ++kk)
                af[mi][kk] = *reinterpret_cast<const bf16x8*>(
                    (char*)&As[cur][0] + ra * 128 + (((kk * 4 + g) ^ sw7) << 4));
        }
#pragma unroll
        for (int ni = 0; ni < 2; ++ni) {
            const int rb = wc * 32 + ni * 16 + li;
#pragma unroll
            for (int kk = 0; kk < 2; ++kk)
                bf[ni][kk] = *reinterpret_cast<const bf16x8*>(
                    (char*)&Bs[cur][0] + rb * 128 + (((kk * 4 + g) ^ sw7) << 4));
        }
        __builtin_amdgcn_s_setprio(1);
#pragma unroll
        for (int mi = 0; mi < 4; ++mi)
#pragma unroll
            for (int ni = 0; ni < 2; ++ni) {
                f32x4 c_ = acc[mi][ni];
                c_ = MFMA16(af[mi][0], bf[ni][0], c_);
                c_ = MFMA16(af[mi][1], bf[ni][1], c_);
                acc[mi][ni] = c_;
            }
        __builtin_amdgcn_s_setprio(0);
        cur = nxt;
    }
#undef PSTAGE

#pragma unroll
    for (int mi = 0; mi < 4; ++mi) {
#pragma unroll
        for (int ni = 0; ni < 2; ++ni) {
            const int n = n0 + wc * 32 + ni * 16 + li;
            const float bv = bias[n];
#pragma unroll
            for (int r = 0; r < 4; ++r) {
                const int m = m0 + wr * 64 + mi * 16 + g * 4 + r;
                outf[(size_t)m * 1024 + n] = acc[mi][ni][r] + bv;
            }
        }
    }
}

// ------- flash attention, causal: 8 waves x 16q, QUAD-buffer counted-vmcnt --------
// (r12-exact, proven 54us). q:[BH,2048,64] (scale*log2e prefolded),
// k:[BH,2048,64], vT:[BH,64,2048] bf16.
__global__ __launch_bounds__(512) void attn_k(
    const __bf16* __restrict__ qg, const __bf16* __restrict__ kg,
    const __bf16* __restrict__ vtg, const int* __restrict__ mflag,
    const int* __restrict__ mask, __bf16* __restrict__ ao)
{
    __shared__ __align__(16) __bf16 Ks[4][4096];   // [64 keys][64 d], 16B-slot XOR-swz
    __shared__ __align__(16) __bf16 Vs[4][4096];   // [64 d][64 keys], XOR-swz
    __shared__ __align__(16) __bf16 Ps[8][1024];   // per-wave P [16 q][64 keys], XOR-swz
    const int t = threadIdx.x;
    const int w = t >> 6, lane = t & 63;
    const int li = lane & 15, g = lane >> 4;
    const int xcd = blockIdx.x & 7;
    const int idx = blockIdx.x >> 3;          // 0..63
    const int hg  = xcd * 4 + (idx & 3);      // 0..31
    const int q_  = idx >> 2;                 // 0..15
    const int band = (q_ < 8) ? (15 - q_) : (q_ - 8);
    const int bI = hg >> 4, hI = hg & 15;
    const int iq = band * 128 + w * 16 + li;  // this lane's query row
    const int mydiag = 2 * band + (w >> 2);   // this wave's last 64-key tile
    const int ktmax = 2 * band + 1;           // block's last staged tile (>=1)
    const int rowt = 2 * band + (w >> 2);     // wave's 64-row mask tile
    const size_t hoff = (size_t)hg * (2048 * 64);
    const __bf16* qh = qg + hoff;
    const __bf16* kh = kg + hoff;
    const __bf16* vh = vtg + hoff;
    char* pw = (char*)&Ps[w][0];
    const int sw7 = li & 7;

    // Q B-operand frags: qf[half] = Q[iq][32*half + 8g + j]
    bf16x8 qf[2];
#pragma unroll
    for (int half = 0; half < 2; ++half)
        qf[half] = *reinterpret_cast<const bf16x8*>(&qh[(size_t)iq * 64 + half * 32 + g * 8]);

    f32x4 o[4] = {};                          // O[d=16df+4g+r][q=li]
    float mrun = -1e30f, lrun = 0.0f;         // lrun = per-lane partial (own keys)

    // stage one 64-key tile into buffer BUF: K 8KB + V 8KB, 512 thr x 16B each
#define STAGE(BUF, KT) do {                                                       \
    const int p_ = t * 16;                                                        \
    const int row_ = p_ >> 7, sl_ = (p_ >> 4) & 7;                                \
    const int gc_ = (sl_ ^ (row_ & 7)) << 3;                                      \
    async_copy16(kh + (size_t)(((KT) << 6) + row_) * 64 + gc_,                    \
                 (__bf16*)((char*)(&Ks[0][0]) + (BUF) * 8192 + p_));              \
    async_copy16(vh + (size_t)row_ * 2048 + ((KT) << 6) + gc_,                    \
                 (__bf16*)((char*)(&Vs[0][0]) + (BUF) * 8192 + p_));              \
} while (0)

    // prologue: tiles 0,1 in flight; vmcnt(2) -> tile 0 landed; barrier.
    STAGE(0, 0);
    STAGE(1, 1);
    VM2();
    __builtin_amdgcn_s_barrier();

    int cur = 0;
    for (int kt = 0; kt <= ktmax; ++kt) {
        if (kt + 2 <= ktmax) {
            STAGE((cur + 2) & 3, kt + 2);
            VM2();
        } else {
            asm volatile("s_waitcnt vmcnt(0)" ::: "memory");   // tail only
        }
        __builtin_amdgcn_sched_barrier(0);
        __builtin_amdgcn_s_barrier();
        __builtin_amdgcn_sched_barrier(0);
        if (kt <= mydiag) {
            const char* kb = (char*)&Ks[0][0] + cur * 8192;
            const char* vb = (char*)&Vs[0][0] + cur * 8192;
            // ---- S^T = K Q^T : s[kb_][r] = S[key = 64kt+16kb_+4g+r][q = li]
            f32x4 s[4] = {};
            __builtin_amdgcn_s_setprio(1);
#pragma unroll
            for (int kb_ = 0; kb_ < 4; ++kb_) {
                const int row = kb_ * 16 + li;
#pragma unroll
                for (int half = 0; half < 2; ++half) {
                    bf16x8 kf = *reinterpret_cast<const bf16x8*>(
                        kb + row * 128 + (((half * 4 + g) ^ sw7) << 4));
                    s[kb_] = MFMA16(kf, qf[half], s[kb_]);
                }
            }
            __builtin_amdgcn_s_setprio(0);
            // ---- causal / padding mask (diag tile only; pad path never taken here)
            const bool pflag = (mflag[(bI * 32 + rowt) * 32 + kt] == 0);
            if (pflag || kt == mydiag) {
                const int jb = kt * 64;
#pragma unroll
                for (int kb_ = 0; kb_ < 4; ++kb_)
#pragma unroll
                    for (int r = 0; r < 4; ++r) {
                        const int j0 = jb + kb_ * 16 + 4 * g + r;
                        float v0 = s[kb_][r];
                        if (j0 > iq ||
                            (pflag && mask[((size_t)(bI * 2048 + iq)) * 2048 + j0] == 0))
                            v0 = -1e30f;
                        s[kb_][r] = v0;
                    }
            }
            // ---- online softmax, exp2 domain, defer-max (THR=8)
            float mt = fmaxf(fmaxf(s[0][0], s[0][1]), fmaxf(s[0][2], s[0][3]));
#pragma unroll
            for (int kb_ = 1; kb_ < 4; ++kb_)
                mt = fmaxf(mt, fmaxf(fmaxf(s[kb_][0], s[kb_][1]),
                                     fmaxf(s[kb_][2], s[kb_][3])));
            mt = fmaxf(mt, __shfl_xor(mt, 16));
            mt = fmaxf(mt, __shfl_xor(mt, 32));
            if (!__all(mt <= mrun + 8.0f)) {
                const float mn = fmaxf(mrun, mt);
                const float alpha = exp2f(mrun - mn);
#pragma unroll
                for (int df = 0; df < 4; ++df)
#pragma unroll
                    for (int r = 0; r < 4; ++r) o[df][r] *= alpha;
                lrun *= alpha;
                mrun = mn;
            }
#pragma unroll
            for (int kb_ = 0; kb_ < 4; ++kb_)
#pragma unroll
                for (int r = 0; r < 4; ++r) {
                    const float p = exp2f(s[kb_][r] - mrun);
                    s[kb_][r] = p;
                    lrun += p;
                }
            // ---- P -> per-wave LDS (swizzled), lands in PV B-operand layout
#pragma unroll
            for (int kb_ = 0; kb_ < 4; ++kb_) {
                const unsigned lo = packbf(s[kb_][0], s[kb_][1]);
                const unsigned hi = packbf(s[kb_][2], s[kb_][3]);
                *reinterpret_cast<uint2*>(
                    pw + li * 128 + (((2 * kb_ + (g >> 1)) ^ sw7) << 4) + ((g & 1) << 3)) =
                    make_uint2(lo, hi);
            }
            bf16x8 pb[2];
#pragma unroll
            for (int ks = 0; ks < 2; ++ks)
                pb[ks] = *reinterpret_cast<const bf16x8*>(
                    pw + li * 128 + (((4 * ks + g) ^ sw7) << 4));
            // ---- O += V^T P : A = Vt rows (d), 8 MFMA16
            __builtin_amdgcn_s_setprio(1);
#pragma unroll
            for (int df = 0; df < 4; ++df) {
                const int vrow = df * 16 + li;
#pragma unroll
                for (int ks = 0; ks < 2; ++ks) {
                    bf16x8 vf = *reinterpret_cast<const bf16x8*>(
                        vb + vrow * 128 + (((4 * ks + g) ^ sw7) << 4));
                    o[df] = MFMA16(vf, pb[ks], o[df]);
                }
            }
            __builtin_amdgcn_s_setprio(0);
        }
        cur = (cur + 1) & 3;
    }
#undef STAGE

    // ---- epilogue: finish lrun reduction, normalize, write
    lrun += __shfl_xor(lrun, 16);
    lrun += __shfl_xor(lrun, 32);
    const float inv = 1.0f / lrun;
    __bf16* aor = ao + ((size_t)(bI * 2048 + iq)) * 1024 + hI * 64 + g * 4;
#pragma unroll
    for (int df = 0; df < 4; ++df) {
        bf16x4 st;
#pragma unroll
        for (int r = 0; r < 4; ++r) st[r] = (__bf16)(o[df][r] * inv);
        *reinterpret_cast<bf16x4*>(&aor[df * 16]) = st;
    }
}

// ------------------------------- launch -----------------------------------------
extern "C" void kernel_launch(void* const* d_in, const int* in_sizes, int n_in,
                              void* d_out, int out_size, void* d_ws, size_t ws_size,
                              hipStream_t stream)
{
    const float* x      = (const float*)d_in[0];
    const int*   mask   = (const int*)d_in[1];
    const float* qkv_w  = (const float*)d_in[2];
    const float* qkv_b  = (const float*)d_in[3];
    const float* proj_w = (const float*)d_in[4];
    const float* proj_b = (const float*)d_in[5];
    float* out = (float*)d_out;

    char* ws = (char*)d_ws;
    __bf16* xb    = (__bf16*)(ws + 0);          // 4096x1024        8 MB
    __bf16* wqkv  = (__bf16*)(ws + 8388608);    // 3072x1024        6 MB
    __bf16* wproj = (__bf16*)(ws + 14680064);   // 1024x1024        2 MB
    __bf16* qg    = (__bf16*)(ws + 16777216);   // [32,2048,64]     8 MB
    __bf16* kg    = (__bf16*)(ws + 25165824);   // [32,2048,64]     8 MB
    __bf16* vtg   = (__bf16*)(ws + 33554432);   // [32,64,2048]     8 MB
    __bf16* ao    = (__bf16*)(ws + 41943040);   // 4096x1024        8 MB
    int*    mflag = (int*)(ws + 50331648);      // [2,32,32]        4 KB

    prep_k<<<10240, 256, 0, stream>>>(x, xb, qkv_w, wqkv, proj_w, wproj, mask, mflag);
    gemm_qkv8_k<<<256, 512, 0, stream>>>(xb, wqkv, qkv_b, qg, kg, vtg);
    attn_k<<<512, 512, 0, stream>>>(qg, kg, vtg, mflag, mask, ao);
    gemm_proj_k<<<512, 256, 0, stream>>>(ao, wproj, proj_b, out);
}